// Round 2
// baseline (5258.545 us; speedup 1.0000x reference)
//
#include <hip/hip_runtime.h>
#include <hip/hip_bf16.h>
#include <math.h>

#define B_GRAPHS 32
#define NPG 128
#define N_TOTAL 4096
#define M_TOK 4
#define K_SUB 16
#define S_SUB 16384
#define FLATN 262144
#define H 128
#define NH 4
#define DH 32
#define STEPS 16
#define L_GNN 4
#define L_RO 2
#define EDGE_DIM 5
#define E_GLOB 32768
#define E_INTRA 524288
#define FFN 512

typedef __hip_bfloat16 bf16;

__device__ __forceinline__ float b2f(bf16 v) { return __bfloat162float(v); }
__device__ __forceinline__ bf16 f2b(float v) { return __float2bfloat16(v); }

// ------------------------------------------------------------- utility ---

__global__ void k_zero4(float4* __restrict__ p, int n4) {
    int i = blockIdx.x * 256 + threadIdx.x;
    if (i < n4) p[i] = make_float4(0.f, 0.f, 0.f, 0.f);
}

// ---------------------------------------------------------------- RWSE ----

__global__ void k_adj(const int* __restrict__ ei, float* __restrict__ T) {
    int e = blockIdx.x * 256 + threadIdx.x;
    if (e >= E_GLOB) return;
    int s = ei[e], d = ei[E_GLOB + e];
    int g = s >> 7;
    atomicAdd(&T[(g * 128 + (s & 127)) * 128 + (d & 127)], 1.0f);
}

__global__ void k_rownorm(float* __restrict__ T) {
    int row = blockIdx.x * 4 + (threadIdx.x >> 6);
    int lane = threadIdx.x & 63;
    float* r = T + (size_t)row * 128;
    float v0 = r[lane], v1 = r[lane + 64];
    float s = v0 + v1;
    #pragma unroll
    for (int off = 32; off > 0; off >>= 1) s += __shfl_down(s, off);
    s = __shfl(s, 0);
    float inv = 1.0f / fmaxf(s, 1.0f);
    r[lane] = v0 * inv;
    r[lane + 64] = v1 * inv;
}

#define RW_BPG 32
#define RW_NPB (128 / RW_BPG)

// Per block: one graph's T in LDS; RW_NPB nodes, each a row-vector chain
// r <- r @ T, recording r[i] (= diag(T^s)[i]) each step.
__global__ __launch_bounds__(128) void k_rwse_chain(const float* __restrict__ T,
                                                    float* __restrict__ rwse) {
    __shared__ __align__(16) float Tl[128 * 128];
    __shared__ __align__(16) float rbuf[128];
    int g = blockIdx.x / RW_BPG, nb = blockIdx.x % RW_BPG;
    int tid = threadIdx.x;
    const float* Tg = T + (size_t)g * 16384;
    for (int idx = tid; idx < 16384; idx += 128) Tl[idx] = Tg[idx];
    __syncthreads();
    for (int ln = 0; ln < RW_NPB; ++ln) {
        int i = nb * RW_NPB + ln;
        float rv = Tl[i * 128 + tid];
        rbuf[tid] = rv;
        float* out = rwse + (size_t)(g * 128 + i) * STEPS;
        if (tid == i) out[0] = rv;   // diag(T^1)
        __syncthreads();
        for (int s = 1; s < STEPS; ++s) {
            float acc = 0.f;
            const float4* r4 = (const float4*)rbuf;
            #pragma unroll
            for (int k4 = 0; k4 < 32; ++k4) {
                float4 rr = r4[k4];
                acc += rr.x * Tl[(k4 * 4 + 0) * 128 + tid]
                     + rr.y * Tl[(k4 * 4 + 1) * 128 + tid]
                     + rr.z * Tl[(k4 * 4 + 2) * 128 + tid]
                     + rr.w * Tl[(k4 * 4 + 3) * 128 + tid];
            }
            __syncthreads();
            rbuf[tid] = acc;
            if (tid == i) out[s] = acc;   // diag(T^{s+1})
            __syncthreads();
        }
    }
}

__global__ void k_rwse_head(const float* __restrict__ rwse, const float* __restrict__ rwse_W,
                            const float* __restrict__ rwse_b, const float* __restrict__ atom_emb,
                            const int* __restrict__ x_ids, float* __restrict__ base) {
    int idx = blockIdx.x * 256 + threadIdx.x;   // n*128 + c
    int n = idx >> 7, c = idx & 127;
    const float* r = rwse + (size_t)n * STEPS;
    float acc = rwse_b[c];
    #pragma unroll
    for (int s = 0; s < STEPS; ++s) acc += r[s] * rwse_W[s * H + c];
    acc = fmaxf(acc, 0.f);
    base[idx] = acc + atom_emb[x_ids[n] * H + c];
}

__global__ void k_hinit(const float* __restrict__ base, const int* __restrict__ node_ids,
                        bf16* __restrict__ h) {
    int idx = blockIdx.x * 256 + threadIdx.x;   // f*128 + c
    int f = idx >> 7, c = idx & 127;
    int nidv = node_ids[f];
    int n = min(max(nidv, 0), N_TOTAL - 1);
    float v = base[n * H + c];
    if (nidv < 0) v = 0.f;
    h[idx] = f2b(v);
}

// ---------------------------------------------------------------- GNN -----

__global__ void k_pool(const bf16* __restrict__ h, const int* __restrict__ node_ids,
                       float* __restrict__ gpool) {
    int idx = blockIdx.x * 256 + threadIdx.x;
    int f = idx >> 7, c = idx & 127;
    int n = min(max(node_ids[f], 0), N_TOTAL - 1);
    atomicAdd(&gpool[n * H + c], b2f(h[idx]));   // invalid rows are already zero
}

__global__ void k_gagg(const float* __restrict__ gpool, const float* __restrict__ bond_emb,
                       const int* __restrict__ ei, const int* __restrict__ ea_ids,
                       float* __restrict__ gagg) {
    int idx = blockIdx.x * 256 + threadIdx.x;
    int e = idx >> 7, c = idx & 127;
    int s = ei[e], d = ei[E_GLOB + e];
    float v = fmaxf(gpool[s * H + c] + bond_emb[(ea_ids[e] - 1) * H + c], 0.f);
    atomicAdd(&gagg[d * H + c], v);
}

__global__ void k_zinit(const bf16* __restrict__ h, const float* __restrict__ gagg,
                        const int* __restrict__ node_ids, float* __restrict__ z) {
    int idx = blockIdx.x * 256 + threadIdx.x;
    int f = idx >> 7, c = idx & 127;
    int n = min(max(node_ids[f], 0), N_TOTAL - 1);
    z[idx] = b2f(h[idx]) + gagg[n * H + c];
}

__global__ void k_agg(const bf16* __restrict__ h, const float* __restrict__ bond_emb,
                      const int* __restrict__ iei, const int* __restrict__ iea,
                      float* __restrict__ z) {
    int idx = blockIdx.x * 256 + threadIdx.x;
    int e = idx >> 7, c = idx & 127;
    int s = iei[e], d = iei[E_INTRA + e];
    float v = fmaxf(b2f(h[(size_t)s * H + c]) + bond_emb[(iea[e] - 1) * H + c], 0.f);
    atomicAdd(&z[(size_t)d * H + c], v);
}

#define MLP_RPB 128

// z <- relu(z @ W1 + b1), in place. Thread c holds W1 column c in registers.
__global__ __launch_bounds__(128) void k_mlpA(const float* __restrict__ W1,
                                              const float* __restrict__ b1,
                                              float* __restrict__ z) {
    int c = threadIdx.x;
    float w[128];
    #pragma unroll
    for (int k = 0; k < 128; ++k) w[k] = W1[k * H + c];
    float bc = b1[c];
    __shared__ __align__(16) float zrow[128];
    int base_row = blockIdx.x * MLP_RPB;
    for (int r = 0; r < MLP_RPB; ++r) {
        int row = base_row + r;
        zrow[c] = z[(size_t)row * H + c];
        __syncthreads();
        float acc = bc;
        const float4* z4 = (const float4*)zrow;
        #pragma unroll
        for (int k4 = 0; k4 < 32; ++k4) {
            float4 zv = z4[k4];
            acc += zv.x * w[k4 * 4 + 0] + zv.y * w[k4 * 4 + 1]
                 + zv.z * w[k4 * 4 + 2] + zv.w * w[k4 * 4 + 3];
        }
        __syncthreads();
        z[(size_t)row * H + c] = fmaxf(acc, 0.f);
    }
}

// h <- (h + mid @ W2 + b2) * valid
__global__ __launch_bounds__(128) void k_mlpB(const float* __restrict__ W2,
                                              const float* __restrict__ b2,
                                              const float* __restrict__ z,
                                              const int* __restrict__ node_ids,
                                              bf16* __restrict__ h) {
    int c = threadIdx.x;
    float w[128];
    #pragma unroll
    for (int k = 0; k < 128; ++k) w[k] = W2[k * H + c];
    float bc = b2[c];
    __shared__ __align__(16) float mrow[128];
    int base_row = blockIdx.x * MLP_RPB;
    for (int r = 0; r < MLP_RPB; ++r) {
        int row = base_row + r;
        mrow[c] = z[(size_t)row * H + c];
        __syncthreads();
        float acc = bc;
        const float4* m4 = (const float4*)mrow;
        #pragma unroll
        for (int k4 = 0; k4 < 32; ++k4) {
            float4 zv = m4[k4];
            acc += zv.x * w[k4 * 4 + 0] + zv.y * w[k4 * 4 + 1]
                 + zv.z * w[k4 * 4 + 2] + zv.w * w[k4 * 4 + 3];
        }
        __syncthreads();
        float valid = (node_ids[row] >= 0) ? 1.f : 0.f;
        h[(size_t)row * H + c] = f2b((b2f(h[(size_t)row * H + c]) + acc) * valid);
    }
}

// ------------------------------------------------------------- Readout ---

__global__ void k_tok(const bf16* __restrict__ h, float* __restrict__ htok) {
    int idx = blockIdx.x * 256 + threadIdx.x;   // s*128 + c
    int s = idx >> 7, c = idx & 127;
    htok[idx] = b2f(h[(size_t)s * K_SUB * H + c]);
}

#define XT_STRIDE 132
#define QKV_STRIDE 385
#define RO_NPB 4

__device__ __forceinline__ void ln16(const float* __restrict__ x, float* __restrict__ y,
                                     const float* __restrict__ g, const float* __restrict__ b,
                                     int tid) {
    int t = tid >> 4, sub = tid & 15;
    const float* xr = x + t * XT_STRIDE + sub * 8;
    float4 a = *(const float4*)xr;
    float4 bq = *(const float4*)(xr + 4);
    float s  = a.x + a.y + a.z + a.w + bq.x + bq.y + bq.z + bq.w;
    float ss = a.x * a.x + a.y * a.y + a.z * a.z + a.w * a.w
             + bq.x * bq.x + bq.y * bq.y + bq.z * bq.z + bq.w * bq.w;
    #pragma unroll
    for (int m = 1; m < 16; m <<= 1) { s += __shfl_xor(s, m); ss += __shfl_xor(ss, m); }
    float mu = s * (1.f / 128.f);
    float var = ss * (1.f / 128.f) - mu * mu;
    float inv = rsqrtf(var + 1e-5f);
    float* yr = y + t * XT_STRIDE + sub * 8;
    const float* gp = g + sub * 8;
    const float* bp = b + sub * 8;
    float xv[8] = {a.x, a.y, a.z, a.w, bq.x, bq.y, bq.z, bq.w};
    #pragma unroll
    for (int i = 0; i < 8; ++i) yr[i] = (xv[i] - mu) * inv * gp[i] + bp[i];
}

__global__ __launch_bounds__(256) void k_ro(
    float* __restrict__ htok,
    const float* __restrict__ g1, const float* __restrict__ b1,
    const float* __restrict__ Wqkv, const float* __restrict__ bqkv,
    const float* __restrict__ Wo, const float* __restrict__ bo,
    const float* __restrict__ g2, const float* __restrict__ b2,
    const float* __restrict__ Wf1, const float* __restrict__ bf1,
    const float* __restrict__ Wf2, const float* __restrict__ bf2,
    const float* __restrict__ log_probs, const float* __restrict__ alpha_p) {
    __shared__ __align__(16) float xt[16 * XT_STRIDE];
    __shared__ __align__(16) float xn[16 * XT_STRIDE];
    __shared__ __align__(16) float buf[16 * FFN];   // qkv (stride 385) / mid (stride 512)
    __shared__ float pmat[256];
    __shared__ float lpv[16];
    int tid = threadIdx.x;
    int node0 = blockIdx.x * RO_NPB;
    float alpha = alpha_p[0];

    for (int i = tid; i < 16 * 128; i += 256) {
        int t = i >> 7, c = i & 127;
        xt[t * XT_STRIDE + c] = htok[(size_t)(node0 * 4 + t) * H + c];
    }
    if (tid < 16) {
        float lp = log_probs[node0 * 4 + tid];
        lpv[tid] = isfinite(lp) ? lp : 0.f;
    }
    __syncthreads();

    // LN1
    ln16(xt, xn, g1, b1, tid);
    __syncthreads();

    // QKV: buf[t][col] (stride QKV_STRIDE), col<384
    for (int cb = 0; cb < 2; ++cb) {
        int col = cb * 256 + tid;
        if (col < 384) {
            float acc[16];
            #pragma unroll
            for (int t = 0; t < 16; ++t) acc[t] = 0.f;
            for (int k4 = 0; k4 < 32; ++k4) {
                float w0 = Wqkv[(k4 * 4 + 0) * 384 + col];
                float w1 = Wqkv[(k4 * 4 + 1) * 384 + col];
                float w2 = Wqkv[(k4 * 4 + 2) * 384 + col];
                float w3 = Wqkv[(k4 * 4 + 3) * 384 + col];
                #pragma unroll
                for (int t = 0; t < 16; ++t) {
                    float4 xv = *(const float4*)&xn[t * XT_STRIDE + k4 * 4];
                    acc[t] += xv.x * w0 + xv.y * w1 + xv.z * w2 + xv.w * w3;
                }
            }
            float bb = bqkv[col];
            #pragma unroll
            for (int t = 0; t < 16; ++t) buf[t * QKV_STRIDE + col] = acc[t] + bb;
        }
    }
    __syncthreads();

    // attention scores + softmax: thread = (ln, head, i, j)
    {
        int ln = tid >> 6, hh = (tid >> 4) & 3, ii = (tid >> 2) & 3, jj = tid & 3;
        const float* q = buf + (ln * 4 + ii) * QKV_STRIDE + hh * 32;
        const float* kk = buf + (ln * 4 + jj) * QKV_STRIDE + 128 + hh * 32;
        float sc = 0.f;
        #pragma unroll
        for (int d = 0; d < 32; ++d) sc += q[d] * kk[d];
        sc = sc * 0.17677669529663689f + alpha * lpv[ln * 4 + jj];
        float mx = fmaxf(sc, __shfl_xor(sc, 1));
        mx = fmaxf(mx, __shfl_xor(mx, 2));
        float e = expf(sc - mx);
        float se = e + __shfl_xor(e, 1);
        se += __shfl_xor(se, 2);
        pmat[tid] = e / se;
    }
    __syncthreads();

    // o = p @ v  -> store into xn
    {
        int t = tid >> 4, sub = tid & 15;
        int ln = t >> 2, ii = t & 3;
        #pragma unroll
        for (int q8 = 0; q8 < 8; ++q8) {
            int c = sub * 8 + q8;
            int hh = c >> 5;
            const float* p = pmat + ((ln * 4 + hh) * 4 + ii) * 4;
            float acc = p[0] * buf[(ln * 4 + 0) * QKV_STRIDE + 256 + c]
                      + p[1] * buf[(ln * 4 + 1) * QKV_STRIDE + 256 + c]
                      + p[2] * buf[(ln * 4 + 2) * QKV_STRIDE + 256 + c]
                      + p[3] * buf[(ln * 4 + 3) * QKV_STRIDE + 256 + c];
            xn[t * XT_STRIDE + c] = acc;
        }
    }
    __syncthreads();

    // xt += o @ Wo + bo
    {
        int c = tid & 127, tg = tid >> 7;
        float acc[8];
        #pragma unroll
        for (int t8 = 0; t8 < 8; ++t8) acc[t8] = 0.f;
        for (int k4 = 0; k4 < 32; ++k4) {
            float w0 = Wo[(k4 * 4 + 0) * H + c];
            float w1 = Wo[(k4 * 4 + 1) * H + c];
            float w2 = Wo[(k4 * 4 + 2) * H + c];
            float w3 = Wo[(k4 * 4 + 3) * H + c];
            #pragma unroll
            for (int t8 = 0; t8 < 8; ++t8) {
                float4 xv = *(const float4*)&xn[(tg * 8 + t8) * XT_STRIDE + k4 * 4];
                acc[t8] += xv.x * w0 + xv.y * w1 + xv.z * w2 + xv.w * w3;
            }
        }
        float bb = bo[c];
        #pragma unroll
        for (int t8 = 0; t8 < 8; ++t8) xt[(tg * 8 + t8) * XT_STRIDE + c] += acc[t8] + bb;
    }
    __syncthreads();

    // LN2
    ln16(xt, xn, g2, b2, tid);
    __syncthreads();

    // mid = gelu(xn @ Wf1 + bf1), stride FFN
    for (int cb = 0; cb < 2; ++cb) {
        int col = cb * 256 + tid;
        float acc[16];
        #pragma unroll
        for (int t = 0; t < 16; ++t) acc[t] = 0.f;
        for (int k4 = 0; k4 < 32; ++k4) {
            float w0 = Wf1[(k4 * 4 + 0) * FFN + col];
            float w1 = Wf1[(k4 * 4 + 1) * FFN + col];
            float w2 = Wf1[(k4 * 4 + 2) * FFN + col];
            float w3 = Wf1[(k4 * 4 + 3) * FFN + col];
            #pragma unroll
            for (int t = 0; t < 16; ++t) {
                float4 xv = *(const float4*)&xn[t * XT_STRIDE + k4 * 4];
                acc[t] += xv.x * w0 + xv.y * w1 + xv.z * w2 + xv.w * w3;
            }
        }
        float bb = bf1[col];
        #pragma unroll
        for (int t = 0; t < 16; ++t) {
            float v = acc[t] + bb;
            buf[t * FFN + col] = v * 0.5f * (1.f + erff(v * 0.70710678118654752f));
        }
    }
    __syncthreads();

    // xt += mid @ Wf2 + bf2
    {
        int c = tid & 127, tg = tid >> 7;
        float acc[8];
        #pragma unroll
        for (int t8 = 0; t8 < 8; ++t8) acc[t8] = 0.f;
        for (int k4 = 0; k4 < 128; ++k4) {
            float w0 = Wf2[(k4 * 4 + 0) * H + c];
            float w1 = Wf2[(k4 * 4 + 1) * H + c];
            float w2 = Wf2[(k4 * 4 + 2) * H + c];
            float w3 = Wf2[(k4 * 4 + 3) * H + c];
            #pragma unroll
            for (int t8 = 0; t8 < 8; ++t8) {
                float4 mv = *(const float4*)&buf[(tg * 8 + t8) * FFN + k4 * 4];
                acc[t8] += mv.x * w0 + mv.y * w1 + mv.z * w2 + mv.w * w3;
            }
        }
        float bb = bf2[c];
        #pragma unroll
        for (int t8 = 0; t8 < 8; ++t8) xt[(tg * 8 + t8) * XT_STRIDE + c] += acc[t8] + bb;
    }
    __syncthreads();

    for (int i = tid; i < 16 * 128; i += 256) {
        int t = i >> 7, c = i & 127;
        htok[(size_t)(node0 * 4 + t) * H + c] = xt[t * XT_STRIDE + c];
    }
}

__global__ __launch_bounds__(128) void k_nodeemb(const float* __restrict__ htok,
                                                 const float* __restrict__ og,
                                                 const float* __restrict__ ob,
                                                 float* __restrict__ nemb) {
    int n = blockIdx.x, c = threadIdx.x;
    const float* hr = htok + (size_t)n * 4 * H;
    float v = 0.25f * (hr[c] + hr[H + c] + hr[2 * H + c] + hr[3 * H + c]);
    float s = v, ss = v * v;
    #pragma unroll
    for (int m = 1; m < 64; m <<= 1) { s += __shfl_xor(s, m); ss += __shfl_xor(ss, m); }
    __shared__ float red[4];
    if ((threadIdx.x & 63) == 0) {
        red[(threadIdx.x >> 6) * 2] = s;
        red[(threadIdx.x >> 6) * 2 + 1] = ss;
    }
    __syncthreads();
    s = red[0] + red[2];
    ss = red[1] + red[3];
    float mu = s * (1.f / 128.f);
    float var = ss * (1.f / 128.f) - mu * mu;
    float inv = rsqrtf(var + 1e-5f);
    nemb[(size_t)n * H + c] = (v - mu) * inv * og[c] + ob[c];
}

__global__ __launch_bounds__(128) void k_out(const float* __restrict__ nemb,
                                             float* __restrict__ out) {
    int g = blockIdx.x, c = threadIdx.x;
    float acc = 0.f;
    for (int i = 0; i < 128; ++i) acc += nemb[(size_t)(g * 128 + i) * H + c];
    out[g * H + c] = acc;
}

// ------------------------------------------------------------- launch ----

extern "C" void kernel_launch(void* const* d_in, const int* in_sizes, int n_in,
                              void* d_out, int out_size, void* d_ws, size_t ws_size,
                              hipStream_t stream) {
    (void)in_sizes; (void)n_in; (void)out_size;
    const int* edge_index    = (const int*)d_in[0];
    const int* intra_ei      = (const int*)d_in[1];
    const int* edge_attr_ids = (const int*)d_in[2];
    const int* intra_ea_ids  = (const int*)d_in[3];
    const int* node_ids      = (const int*)d_in[4];
    const int* x_ids         = (const int*)d_in[5];
    // d_in[6] = batch (== n>>7 by construction)
    const float* log_probs   = (const float*)d_in[7];
    const float* atom_emb    = (const float*)d_in[8];
    const float* bond_emb    = (const float*)d_in[9];
    const float* rwse_W      = (const float*)d_in[10];
    const float* rwse_b      = (const float*)d_in[11];
    const float* gnn_W1      = (const float*)d_in[12];
    const float* gnn_b1      = (const float*)d_in[13];
    const float* gnn_W2      = (const float*)d_in[14];
    const float* gnn_b2      = (const float*)d_in[15];
    const float* ro_ln1_g    = (const float*)d_in[16];
    const float* ro_ln1_b    = (const float*)d_in[17];
    const float* ro_Wqkv     = (const float*)d_in[18];
    const float* ro_bqkv     = (const float*)d_in[19];
    const float* ro_Wo       = (const float*)d_in[20];
    const float* ro_bo       = (const float*)d_in[21];
    const float* ro_ln2_g    = (const float*)d_in[22];
    const float* ro_ln2_b    = (const float*)d_in[23];
    const float* ro_Wf1      = (const float*)d_in[24];
    const float* ro_bf1      = (const float*)d_in[25];
    const float* ro_Wf2      = (const float*)d_in[26];
    const float* ro_bf2      = (const float*)d_in[27];
    const float* out_ln_g    = (const float*)d_in[28];
    const float* out_ln_b    = (const float*)d_in[29];
    const float* ht_alpha    = (const float*)d_in[30];

    char* ws = (char*)d_ws;
    size_t off = 0;
    auto alloc = [&](size_t nbytes) {
        char* p = ws + off;
        off += (nbytes + 255) & ~(size_t)255;
        return p;
    };
    float* T     = (float*)alloc((size_t)B_GRAPHS * 128 * 128 * 4);
    float* rwse  = (float*)alloc((size_t)N_TOTAL * STEPS * 4);
    float* base  = (float*)alloc((size_t)N_TOTAL * H * 4);
    float* gbuf  = (float*)alloc((size_t)2 * N_TOTAL * H * 4);  // gpool | gagg contiguous
    float* htok  = (float*)alloc((size_t)S_SUB * H * 4);
    float* nemb  = (float*)alloc((size_t)N_TOTAL * H * 4);
    float* z     = (float*)alloc((size_t)FLATN * H * 4);
    bf16*  h     = (bf16*)alloc((size_t)FLATN * H * 2);
    float* gpool = gbuf;
    float* gagg  = gbuf + (size_t)N_TOTAL * H;

    if (off > ws_size) return;   // diagnostic guard: fail cleanly, not with a GPU fault

    // T = 0
    k_zero4<<<(B_GRAPHS * 128 * 128 / 4 + 255) / 256, 256, 0, stream>>>((float4*)T, B_GRAPHS * 128 * 128 / 4);
    k_adj<<<E_GLOB / 256, 256, 0, stream>>>(edge_index, T);
    k_rownorm<<<(B_GRAPHS * 128) / 4, 256, 0, stream>>>(T);
    k_rwse_chain<<<B_GRAPHS * RW_BPG, 128, 0, stream>>>(T, rwse);
    k_rwse_head<<<(N_TOTAL * H) / 256, 256, 0, stream>>>(rwse, rwse_W, rwse_b, atom_emb, x_ids, base);
    k_hinit<<<(FLATN * H) / 256, 256, 0, stream>>>(base, node_ids, h);

    for (int l = 0; l < L_GNN; ++l) {
        k_zero4<<<(2 * N_TOTAL * H / 4 + 255) / 256, 256, 0, stream>>>((float4*)gbuf, 2 * N_TOTAL * H / 4);
        k_pool<<<(FLATN * H) / 256, 256, 0, stream>>>(h, node_ids, gpool);
        k_gagg<<<(E_GLOB * H) / 256, 256, 0, stream>>>(gpool, bond_emb, edge_index, edge_attr_ids, gagg);
        k_zinit<<<(FLATN * H) / 256, 256, 0, stream>>>(h, gagg, node_ids, z);
        k_agg<<<(E_INTRA / 2), 256, 0, stream>>>(h, bond_emb, intra_ei, intra_ea_ids, z);
        k_mlpA<<<FLATN / MLP_RPB, 128, 0, stream>>>(gnn_W1 + (size_t)l * H * H, gnn_b1 + l * H, z);
        k_mlpB<<<FLATN / MLP_RPB, 128, 0, stream>>>(gnn_W2 + (size_t)l * H * H, gnn_b2 + l * H, z, node_ids, h);
    }

    k_tok<<<(S_SUB * H) / 256, 256, 0, stream>>>(h, htok);
    for (int l = 0; l < L_RO; ++l) {
        k_ro<<<N_TOTAL / RO_NPB, 256, 0, stream>>>(htok,
            ro_ln1_g + l * H, ro_ln1_b + l * H,
            ro_Wqkv + (size_t)l * H * 3 * H, ro_bqkv + l * 3 * H,
            ro_Wo + (size_t)l * H * H, ro_bo + l * H,
            ro_ln2_g + l * H, ro_ln2_b + l * H,
            ro_Wf1 + (size_t)l * H * FFN, ro_bf1 + l * FFN,
            ro_Wf2 + (size_t)l * FFN * H, ro_bf2 + l * H,
            log_probs, ht_alpha);
    }
    k_nodeemb<<<N_TOTAL, 128, 0, stream>>>(htok, out_ln_g, out_ln_b, nemb);
    k_out<<<B_GRAPHS, 128, 0, stream>>>(nemb, (float*)d_out);
}

// Round 3
// 2554.211 us; speedup vs baseline: 2.0588x; 2.0588x over previous
//
#include <hip/hip_runtime.h>
#include <hip/hip_bf16.h>
#include <math.h>

#define B_GRAPHS 32
#define NPG 128
#define N_TOTAL 4096
#define M_TOK 4
#define K_SUB 16
#define S_SUB 16384
#define FLATN 262144
#define H 128
#define NH 4
#define DH 32
#define STEPS 16
#define L_GNN 4
#define L_RO 2
#define EDGE_DIM 5
#define E_GLOB 32768
#define E_INTRA 524288
#define FFN 512

typedef __hip_bfloat16 bf16;
typedef __attribute__((ext_vector_type(8))) short s16x8;
typedef __attribute__((ext_vector_type(4))) float f32x4;

__device__ __forceinline__ float b2f(bf16 v) { return __bfloat162float(v); }
__device__ __forceinline__ bf16 f2b(float v) { return __float2bfloat16(v); }
__device__ __forceinline__ unsigned short f2bu(float v) {
    bf16 b = __float2bfloat16(v);
    return *(unsigned short*)&b;
}

// ------------------------------------------------------------- utility ---

__global__ void k_zero4(float4* __restrict__ p, int n4) {
    int i = blockIdx.x * 256 + threadIdx.x;
    if (i < n4) p[i] = make_float4(0.f, 0.f, 0.f, 0.f);
}

// ---------------------------------------------------------------- RWSE ----

__global__ void k_adj(const int* __restrict__ ei, float* __restrict__ T) {
    int e = blockIdx.x * 256 + threadIdx.x;
    if (e >= E_GLOB) return;
    int s = ei[e], d = ei[E_GLOB + e];
    int g = s >> 7;
    atomicAdd(&T[(g * 128 + (s & 127)) * 128 + (d & 127)], 1.0f);
}

__global__ void k_rownorm(float* __restrict__ T) {
    int row = blockIdx.x * 4 + (threadIdx.x >> 6);
    int lane = threadIdx.x & 63;
    float* r = T + (size_t)row * 128;
    float v0 = r[lane], v1 = r[lane + 64];
    float s = v0 + v1;
    #pragma unroll
    for (int off = 32; off > 0; off >>= 1) s += __shfl_down(s, off);
    s = __shfl(s, 0);
    float inv = 1.0f / fmaxf(s, 1.0f);
    r[lane] = v0 * inv;
    r[lane + 64] = v1 * inv;
}

#define RW_BPG 32
#define RW_NPB (128 / RW_BPG)

__global__ __launch_bounds__(128) void k_rwse_chain(const float* __restrict__ T,
                                                    float* __restrict__ rwse) {
    __shared__ __align__(16) float Tl[128 * 128];
    __shared__ __align__(16) float rbuf[128];
    int g = blockIdx.x / RW_BPG, nb = blockIdx.x % RW_BPG;
    int tid = threadIdx.x;
    const float* Tg = T + (size_t)g * 16384;
    for (int idx = tid; idx < 16384; idx += 128) Tl[idx] = Tg[idx];
    __syncthreads();
    for (int ln = 0; ln < RW_NPB; ++ln) {
        int i = nb * RW_NPB + ln;
        float rv = Tl[i * 128 + tid];
        rbuf[tid] = rv;
        float* out = rwse + (size_t)(g * 128 + i) * STEPS;
        if (tid == i) out[0] = rv;
        __syncthreads();
        for (int s = 1; s < STEPS; ++s) {
            float acc = 0.f;
            const float4* r4 = (const float4*)rbuf;
            #pragma unroll
            for (int k4 = 0; k4 < 32; ++k4) {
                float4 rr = r4[k4];
                acc += rr.x * Tl[(k4 * 4 + 0) * 128 + tid]
                     + rr.y * Tl[(k4 * 4 + 1) * 128 + tid]
                     + rr.z * Tl[(k4 * 4 + 2) * 128 + tid]
                     + rr.w * Tl[(k4 * 4 + 3) * 128 + tid];
            }
            __syncthreads();
            rbuf[tid] = acc;
            if (tid == i) out[s] = acc;
            __syncthreads();
        }
    }
}

__global__ void k_rwse_head(const float* __restrict__ rwse, const float* __restrict__ rwse_W,
                            const float* __restrict__ rwse_b, const float* __restrict__ atom_emb,
                            const int* __restrict__ x_ids, float* __restrict__ base) {
    int idx = blockIdx.x * 256 + threadIdx.x;
    int n = idx >> 7, c = idx & 127;
    const float* r = rwse + (size_t)n * STEPS;
    float acc = rwse_b[c];
    #pragma unroll
    for (int s = 0; s < STEPS; ++s) acc += r[s] * rwse_W[s * H + c];
    acc = fmaxf(acc, 0.f);
    base[idx] = acc + atom_emb[x_ids[n] * H + c];
}

__global__ void k_hinit(const float* __restrict__ base, const int* __restrict__ node_ids,
                        bf16* __restrict__ h) {
    int idx = blockIdx.x * 256 + threadIdx.x;
    int f = idx >> 7, c = idx & 127;
    int nidv = node_ids[f];
    int n = min(max(nidv, 0), N_TOTAL - 1);
    float v = base[n * H + c];
    if (nidv < 0) v = 0.f;
    h[idx] = f2b(v);
}

// ---------------------------------------------------------------- GNN -----

__global__ void k_pool(const bf16* __restrict__ h, const int* __restrict__ node_ids,
                       float* __restrict__ gpool) {
    int idx = blockIdx.x * 256 + threadIdx.x;
    int f = idx >> 7, c = idx & 127;
    int n = min(max(node_ids[f], 0), N_TOTAL - 1);
    atomicAdd(&gpool[n * H + c], b2f(h[idx]));
}

__global__ void k_gagg(const float* __restrict__ gpool, const float* __restrict__ bond_emb,
                       const int* __restrict__ ei, const int* __restrict__ ea_ids,
                       float* __restrict__ gagg) {
    int idx = blockIdx.x * 256 + threadIdx.x;
    int e = idx >> 7, c = idx & 127;
    int s = ei[e], d = ei[E_GLOB + e];
    float v = fmaxf(gpool[s * H + c] + bond_emb[(ea_ids[e] - 1) * H + c], 0.f);
    atomicAdd(&gagg[d * H + c], v);
}

__global__ void k_zinit(const bf16* __restrict__ h, const float* __restrict__ gagg,
                        const int* __restrict__ node_ids, float* __restrict__ z) {
    int idx = blockIdx.x * 256 + threadIdx.x;
    int f = idx >> 7, c = idx & 127;
    int n = min(max(node_ids[f], 0), N_TOTAL - 1);
    z[idx] = b2f(h[idx]) + gagg[n * H + c];
}

__global__ void k_agg(const bf16* __restrict__ h, const float* __restrict__ bond_emb,
                      const int* __restrict__ iei, const int* __restrict__ iea,
                      float* __restrict__ z) {
    int idx = blockIdx.x * 256 + threadIdx.x;
    int e = idx >> 7, c = idx & 127;
    int s = iei[e], d = iei[E_INTRA + e];
    float v = fmaxf(b2f(h[(size_t)s * H + c]) + bond_emb[(iea[e] - 1) * H + c], 0.f);
    atomicAdd(&z[(size_t)d * H + c], v);
}

// Fused GINE MLP: h = (h + W2@relu(W1@z + b1) + b2) * valid, all matmul in
// bf16 MFMA 16x16x32. Block = 256 thr (4 waves), BM=128 rows; wave w owns
// output columns [32w, 32w+32).
#define LDW 136   // LDS row stride (elements): 272B, 16B-aligned

__global__ __launch_bounds__(256) void k_mlp_fused(
    const float* __restrict__ W1, const float* __restrict__ b1,
    const float* __restrict__ W2, const float* __restrict__ b2,
    const float* __restrict__ z, const int* __restrict__ node_ids,
    bf16* __restrict__ h) {
    __shared__ unsigned short zt[128][LDW];
    __shared__ unsigned short mt[128][LDW];
    __shared__ float validf[128];

    int tid = threadIdx.x;
    int w = tid >> 6;          // wave 0..3
    int l = tid & 63;          // lane
    int brow0 = blockIdx.x * 128;

    // --- stage z tile (fp32 -> bf16) + valid flags ---
    {
        int r = tid >> 1, c0 = (tid & 1) * 64;
        const float4* zr = (const float4*)(z + (size_t)(brow0 + r) * H + c0);
        #pragma unroll
        for (int i = 0; i < 16; ++i) {
            float4 v = zr[i];
            ushort4 u;
            u.x = f2bu(v.x); u.y = f2bu(v.y); u.z = f2bu(v.z); u.w = f2bu(v.w);
            *(ushort4*)&zt[r][c0 + i * 4] = u;
        }
        if (tid < 128) validf[tid] = (node_ids[brow0 + tid] >= 0) ? 1.f : 0.f;
    }

    // --- W1/W2 fragments for my 32 columns (fp32 -> bf16), L2-resident ---
    s16x8 bw1[2][4], bw2[2][4];
    float b1c[2], b2c[2];
    #pragma unroll
    for (int nt = 0; nt < 2; ++nt) {
        int col = w * 32 + nt * 16 + (l & 15);
        b1c[nt] = b1[col];
        b2c[nt] = b2[col];
        #pragma unroll
        for (int kt = 0; kt < 4; ++kt) {
            int k0 = kt * 32 + (l >> 4) * 8;
            #pragma unroll
            for (int j = 0; j < 8; ++j) {
                bw1[nt][kt][j] = (short)f2bu(W1[(size_t)(k0 + j) * H + col]);
                bw2[nt][kt][j] = (short)f2bu(W2[(size_t)(k0 + j) * H + col]);
            }
        }
    }
    __syncthreads();

    // --- GEMM1: mid = relu(z @ W1 + b1) ---
    f32x4 acc[8][2];
    #pragma unroll
    for (int mt_i = 0; mt_i < 8; ++mt_i)
        #pragma unroll
        for (int nt = 0; nt < 2; ++nt)
            acc[mt_i][nt] = f32x4{0.f, 0.f, 0.f, 0.f};
    #pragma unroll
    for (int kt = 0; kt < 4; ++kt) {
        #pragma unroll
        for (int mt_i = 0; mt_i < 8; ++mt_i) {
            s16x8 a = *(const s16x8*)&zt[mt_i * 16 + (l & 15)][kt * 32 + (l >> 4) * 8];
            acc[mt_i][0] = __builtin_amdgcn_mfma_f32_16x16x32_bf16(a, bw1[0][kt], acc[mt_i][0], 0, 0, 0);
            acc[mt_i][1] = __builtin_amdgcn_mfma_f32_16x16x32_bf16(a, bw1[1][kt], acc[mt_i][1], 0, 0, 0);
        }
    }
    // write mid (bf16) to LDS: C/D layout col=lane&15, row=(lane>>4)*4+reg
    #pragma unroll
    for (int mt_i = 0; mt_i < 8; ++mt_i) {
        #pragma unroll
        for (int nt = 0; nt < 2; ++nt) {
            int col = w * 32 + nt * 16 + (l & 15);
            #pragma unroll
            for (int r = 0; r < 4; ++r) {
                int row = mt_i * 16 + (l >> 4) * 4 + r;
                mt[row][col] = f2bu(fmaxf(acc[mt_i][nt][r] + b1c[nt], 0.f));
            }
        }
    }
    __syncthreads();

    // --- GEMM2: out = mid @ W2 ---
    #pragma unroll
    for (int mt_i = 0; mt_i < 8; ++mt_i)
        #pragma unroll
        for (int nt = 0; nt < 2; ++nt)
            acc[mt_i][nt] = f32x4{0.f, 0.f, 0.f, 0.f};
    #pragma unroll
    for (int kt = 0; kt < 4; ++kt) {
        #pragma unroll
        for (int mt_i = 0; mt_i < 8; ++mt_i) {
            s16x8 a = *(const s16x8*)&mt[mt_i * 16 + (l & 15)][kt * 32 + (l >> 4) * 8];
            acc[mt_i][0] = __builtin_amdgcn_mfma_f32_16x16x32_bf16(a, bw2[0][kt], acc[mt_i][0], 0, 0, 0);
            acc[mt_i][1] = __builtin_amdgcn_mfma_f32_16x16x32_bf16(a, bw2[1][kt], acc[mt_i][1], 0, 0, 0);
        }
    }
    // epilogue: h = (h + out + b2) * valid
    #pragma unroll
    for (int mt_i = 0; mt_i < 8; ++mt_i) {
        #pragma unroll
        for (int nt = 0; nt < 2; ++nt) {
            int col = w * 32 + nt * 16 + (l & 15);
            #pragma unroll
            for (int r = 0; r < 4; ++r) {
                int row = mt_i * 16 + (l >> 4) * 4 + r;
                size_t g = (size_t)(brow0 + row) * H + col;
                float hv = b2f(h[g]);
                h[g] = f2b((hv + acc[mt_i][nt][r] + b2c[nt]) * validf[row]);
            }
        }
    }
}

// ------------------------------------------------------------- Readout ---

__global__ void k_tok(const bf16* __restrict__ h, float* __restrict__ htok) {
    int idx = blockIdx.x * 256 + threadIdx.x;
    int s = idx >> 7, c = idx & 127;
    htok[idx] = b2f(h[(size_t)s * K_SUB * H + c]);
}

#define XT_STRIDE 132
#define QKV_STRIDE 385
#define RO_NPB 4

__device__ __forceinline__ void ln16(const float* __restrict__ x, float* __restrict__ y,
                                     const float* __restrict__ g, const float* __restrict__ b,
                                     int tid) {
    int t = tid >> 4, sub = tid & 15;
    const float* xr = x + t * XT_STRIDE + sub * 8;
    float4 a = *(const float4*)xr;
    float4 bq = *(const float4*)(xr + 4);
    float s  = a.x + a.y + a.z + a.w + bq.x + bq.y + bq.z + bq.w;
    float ss = a.x * a.x + a.y * a.y + a.z * a.z + a.w * a.w
             + bq.x * bq.x + bq.y * bq.y + bq.z * bq.z + bq.w * bq.w;
    #pragma unroll
    for (int m = 1; m < 16; m <<= 1) { s += __shfl_xor(s, m); ss += __shfl_xor(ss, m); }
    float mu = s * (1.f / 128.f);
    float var = ss * (1.f / 128.f) - mu * mu;
    float inv = rsqrtf(var + 1e-5f);
    float* yr = y + t * XT_STRIDE + sub * 8;
    const float* gp = g + sub * 8;
    const float* bp = b + sub * 8;
    float xv[8] = {a.x, a.y, a.z, a.w, bq.x, bq.y, bq.z, bq.w};
    #pragma unroll
    for (int i = 0; i < 8; ++i) yr[i] = (xv[i] - mu) * inv * gp[i] + bp[i];
}

__global__ __launch_bounds__(256) void k_ro(
    float* __restrict__ htok,
    const float* __restrict__ g1, const float* __restrict__ b1,
    const float* __restrict__ Wqkv, const float* __restrict__ bqkv,
    const float* __restrict__ Wo, const float* __restrict__ bo,
    const float* __restrict__ g2, const float* __restrict__ b2,
    const float* __restrict__ Wf1, const float* __restrict__ bf1,
    const float* __restrict__ Wf2, const float* __restrict__ bf2,
    const float* __restrict__ log_probs, const float* __restrict__ alpha_p) {
    __shared__ __align__(16) float xt[16 * XT_STRIDE];
    __shared__ __align__(16) float xn[16 * XT_STRIDE];
    __shared__ __align__(16) float buf[16 * FFN];
    __shared__ float pmat[256];
    __shared__ float lpv[16];
    int tid = threadIdx.x;
    int node0 = blockIdx.x * RO_NPB;
    float alpha = alpha_p[0];

    for (int i = tid; i < 16 * 128; i += 256) {
        int t = i >> 7, c = i & 127;
        xt[t * XT_STRIDE + c] = htok[(size_t)(node0 * 4 + t) * H + c];
    }
    if (tid < 16) {
        float lp = log_probs[node0 * 4 + tid];
        lpv[tid] = isfinite(lp) ? lp : 0.f;
    }
    __syncthreads();

    ln16(xt, xn, g1, b1, tid);
    __syncthreads();

    for (int cb = 0; cb < 2; ++cb) {
        int col = cb * 256 + tid;
        if (col < 384) {
            float acc[16];
            #pragma unroll
            for (int t = 0; t < 16; ++t) acc[t] = 0.f;
            for (int k4 = 0; k4 < 32; ++k4) {
                float w0 = Wqkv[(k4 * 4 + 0) * 384 + col];
                float w1 = Wqkv[(k4 * 4 + 1) * 384 + col];
                float w2 = Wqkv[(k4 * 4 + 2) * 384 + col];
                float w3 = Wqkv[(k4 * 4 + 3) * 384 + col];
                #pragma unroll
                for (int t = 0; t < 16; ++t) {
                    float4 xv = *(const float4*)&xn[t * XT_STRIDE + k4 * 4];
                    acc[t] += xv.x * w0 + xv.y * w1 + xv.z * w2 + xv.w * w3;
                }
            }
            float bb = bqkv[col];
            #pragma unroll
            for (int t = 0; t < 16; ++t) buf[t * QKV_STRIDE + col] = acc[t] + bb;
        }
    }
    __syncthreads();

    {
        int ln = tid >> 6, hh = (tid >> 4) & 3, ii = (tid >> 2) & 3, jj = tid & 3;
        const float* q = buf + (ln * 4 + ii) * QKV_STRIDE + hh * 32;
        const float* kk = buf + (ln * 4 + jj) * QKV_STRIDE + 128 + hh * 32;
        float sc = 0.f;
        #pragma unroll
        for (int d = 0; d < 32; ++d) sc += q[d] * kk[d];
        sc = sc * 0.17677669529663689f + alpha * lpv[ln * 4 + jj];
        float mx = fmaxf(sc, __shfl_xor(sc, 1));
        mx = fmaxf(mx, __shfl_xor(mx, 2));
        float e = expf(sc - mx);
        float se = e + __shfl_xor(e, 1);
        se += __shfl_xor(se, 2);
        pmat[tid] = e / se;
    }
    __syncthreads();

    {
        int t = tid >> 4, sub = tid & 15;
        int ln = t >> 2, ii = t & 3;
        #pragma unroll
        for (int q8 = 0; q8 < 8; ++q8) {
            int c = sub * 8 + q8;
            int hh = c >> 5;
            const float* p = pmat + ((ln * 4 + hh) * 4 + ii) * 4;
            float acc = p[0] * buf[(ln * 4 + 0) * QKV_STRIDE + 256 + c]
                      + p[1] * buf[(ln * 4 + 1) * QKV_STRIDE + 256 + c]
                      + p[2] * buf[(ln * 4 + 2) * QKV_STRIDE + 256 + c]
                      + p[3] * buf[(ln * 4 + 3) * QKV_STRIDE + 256 + c];
            xn[t * XT_STRIDE + c] = acc;
        }
    }
    __syncthreads();

    {
        int c = tid & 127, tg = tid >> 7;
        float acc[8];
        #pragma unroll
        for (int t8 = 0; t8 < 8; ++t8) acc[t8] = 0.f;
        for (int k4 = 0; k4 < 32; ++k4) {
            float w0 = Wo[(k4 * 4 + 0) * H + c];
            float w1 = Wo[(k4 * 4 + 1) * H + c];
            float w2 = Wo[(k4 * 4 + 2) * H + c];
            float w3 = Wo[(k4 * 4 + 3) * H + c];
            #pragma unroll
            for (int t8 = 0; t8 < 8; ++t8) {
                float4 xv = *(const float4*)&xn[(tg * 8 + t8) * XT_STRIDE + k4 * 4];
                acc[t8] += xv.x * w0 + xv.y * w1 + xv.z * w2 + xv.w * w3;
            }
        }
        float bb = bo[c];
        #pragma unroll
        for (int t8 = 0; t8 < 8; ++t8) xt[(tg * 8 + t8) * XT_STRIDE + c] += acc[t8] + bb;
    }
    __syncthreads();

    ln16(xt, xn, g2, b2, tid);
    __syncthreads();

    for (int cb = 0; cb < 2; ++cb) {
        int col = cb * 256 + tid;
        float acc[16];
        #pragma unroll
        for (int t = 0; t < 16; ++t) acc[t] = 0.f;
        for (int k4 = 0; k4 < 32; ++k4) {
            float w0 = Wf1[(k4 * 4 + 0) * FFN + col];
            float w1 = Wf1[(k4 * 4 + 1) * FFN + col];
            float w2 = Wf1[(k4 * 4 + 2) * FFN + col];
            float w3 = Wf1[(k4 * 4 + 3) * FFN + col];
            #pragma unroll
            for (int t = 0; t < 16; ++t) {
                float4 xv = *(const float4*)&xn[t * XT_STRIDE + k4 * 4];
                acc[t] += xv.x * w0 + xv.y * w1 + xv.z * w2 + xv.w * w3;
            }
        }
        float bb = bf1[col];
        #pragma unroll
        for (int t = 0; t < 16; ++t) {
            float v = acc[t] + bb;
            buf[t * FFN + col] = v * 0.5f * (1.f + erff(v * 0.70710678118654752f));
        }
    }
    __syncthreads();

    {
        int c = tid & 127, tg = tid >> 7;
        float acc[8];
        #pragma unroll
        for (int t8 = 0; t8 < 8; ++t8) acc[t8] = 0.f;
        for (int k4 = 0; k4 < 128; ++k4) {
            float w0 = Wf2[(k4 * 4 + 0) * H + c];
            float w1 = Wf2[(k4 * 4 + 1) * H + c];
            float w2 = Wf2[(k4 * 4 + 2) * H + c];
            float w3 = Wf2[(k4 * 4 + 3) * H + c];
            #pragma unroll
            for (int t8 = 0; t8 < 8; ++t8) {
                float4 mv = *(const float4*)&buf[(tg * 8 + t8) * FFN + k4 * 4];
                acc[t8] += mv.x * w0 + mv.y * w1 + mv.z * w2 + mv.w * w3;
            }
        }
        float bb = bf2[c];
        #pragma unroll
        for (int t8 = 0; t8 < 8; ++t8) xt[(tg * 8 + t8) * XT_STRIDE + c] += acc[t8] + bb;
    }
    __syncthreads();

    for (int i = tid; i < 16 * 128; i += 256) {
        int t = i >> 7, c = i & 127;
        htok[(size_t)(node0 * 4 + t) * H + c] = xt[t * XT_STRIDE + c];
    }
}

__global__ __launch_bounds__(128) void k_nodeemb(const float* __restrict__ htok,
                                                 const float* __restrict__ og,
                                                 const float* __restrict__ ob,
                                                 float* __restrict__ nemb) {
    int n = blockIdx.x, c = threadIdx.x;
    const float* hr = htok + (size_t)n * 4 * H;
    float v = 0.25f * (hr[c] + hr[H + c] + hr[2 * H + c] + hr[3 * H + c]);
    float s = v, ss = v * v;
    #pragma unroll
    for (int m = 1; m < 64; m <<= 1) { s += __shfl_xor(s, m); ss += __shfl_xor(ss, m); }
    __shared__ float red[4];
    if ((threadIdx.x & 63) == 0) {
        red[(threadIdx.x >> 6) * 2] = s;
        red[(threadIdx.x >> 6) * 2 + 1] = ss;
    }
    __syncthreads();
    s = red[0] + red[2];
    ss = red[1] + red[3];
    float mu = s * (1.f / 128.f);
    float var = ss * (1.f / 128.f) - mu * mu;
    float inv = rsqrtf(var + 1e-5f);
    nemb[(size_t)n * H + c] = (v - mu) * inv * og[c] + ob[c];
}

__global__ __launch_bounds__(128) void k_out(const float* __restrict__ nemb,
                                             float* __restrict__ out) {
    int g = blockIdx.x, c = threadIdx.x;
    float acc = 0.f;
    for (int i = 0; i < 128; ++i) acc += nemb[(size_t)(g * 128 + i) * H + c];
    out[g * H + c] = acc;
}

// ------------------------------------------------------------- launch ----

extern "C" void kernel_launch(void* const* d_in, const int* in_sizes, int n_in,
                              void* d_out, int out_size, void* d_ws, size_t ws_size,
                              hipStream_t stream) {
    (void)in_sizes; (void)n_in; (void)out_size;
    const int* edge_index    = (const int*)d_in[0];
    const int* intra_ei      = (const int*)d_in[1];
    const int* edge_attr_ids = (const int*)d_in[2];
    const int* intra_ea_ids  = (const int*)d_in[3];
    const int* node_ids      = (const int*)d_in[4];
    const int* x_ids         = (const int*)d_in[5];
    const float* log_probs   = (const float*)d_in[7];
    const float* atom_emb    = (const float*)d_in[8];
    const float* bond_emb    = (const float*)d_in[9];
    const float* rwse_W      = (const float*)d_in[10];
    const float* rwse_b      = (const float*)d_in[11];
    const float* gnn_W1      = (const float*)d_in[12];
    const float* gnn_b1      = (const float*)d_in[13];
    const float* gnn_W2      = (const float*)d_in[14];
    const float* gnn_b2      = (const float*)d_in[15];
    const float* ro_ln1_g    = (const float*)d_in[16];
    const float* ro_ln1_b    = (const float*)d_in[17];
    const float* ro_Wqkv     = (const float*)d_in[18];
    const float* ro_bqkv     = (const float*)d_in[19];
    const float* ro_Wo       = (const float*)d_in[20];
    const float* ro_bo       = (const float*)d_in[21];
    const float* ro_ln2_g    = (const float*)d_in[22];
    const float* ro_ln2_b    = (const float*)d_in[23];
    const float* ro_Wf1      = (const float*)d_in[24];
    const float* ro_bf1      = (const float*)d_in[25];
    const float* ro_Wf2      = (const float*)d_in[26];
    const float* ro_bf2      = (const float*)d_in[27];
    const float* out_ln_g    = (const float*)d_in[28];
    const float* out_ln_b    = (const float*)d_in[29];
    const float* ht_alpha    = (const float*)d_in[30];

    char* ws = (char*)d_ws;
    size_t off = 0;
    auto alloc = [&](size_t nbytes) {
        char* p = ws + off;
        off += (nbytes + 255) & ~(size_t)255;
        return p;
    };
    float* T     = (float*)alloc((size_t)B_GRAPHS * 128 * 128 * 4);
    float* rwse  = (float*)alloc((size_t)N_TOTAL * STEPS * 4);
    float* base  = (float*)alloc((size_t)N_TOTAL * H * 4);
    float* gbuf  = (float*)alloc((size_t)2 * N_TOTAL * H * 4);
    float* htok  = (float*)alloc((size_t)S_SUB * H * 4);
    float* nemb  = (float*)alloc((size_t)N_TOTAL * H * 4);
    float* z     = (float*)alloc((size_t)FLATN * H * 4);
    bf16*  h     = (bf16*)alloc((size_t)FLATN * H * 2);
    float* gpool = gbuf;
    float* gagg  = gbuf + (size_t)N_TOTAL * H;

    if (off > ws_size) return;

    k_zero4<<<(B_GRAPHS * 128 * 128 / 4 + 255) / 256, 256, 0, stream>>>((float4*)T, B_GRAPHS * 128 * 128 / 4);
    k_adj<<<E_GLOB / 256, 256, 0, stream>>>(edge_index, T);
    k_rownorm<<<(B_GRAPHS * 128) / 4, 256, 0, stream>>>(T);
    k_rwse_chain<<<B_GRAPHS * RW_BPG, 128, 0, stream>>>(T, rwse);
    k_rwse_head<<<(N_TOTAL * H) / 256, 256, 0, stream>>>(rwse, rwse_W, rwse_b, atom_emb, x_ids, base);
    k_hinit<<<(FLATN * H) / 256, 256, 0, stream>>>(base, node_ids, h);

    for (int l = 0; l < L_GNN; ++l) {
        k_zero4<<<(2 * N_TOTAL * H / 4 + 255) / 256, 256, 0, stream>>>((float4*)gbuf, 2 * N_TOTAL * H / 4);
        k_pool<<<(FLATN * H) / 256, 256, 0, stream>>>(h, node_ids, gpool);
        k_gagg<<<(E_GLOB * H) / 256, 256, 0, stream>>>(gpool, bond_emb, edge_index, edge_attr_ids, gagg);
        k_zinit<<<(FLATN * H) / 256, 256, 0, stream>>>(h, gagg, node_ids, z);
        k_agg<<<(E_INTRA / 2), 256, 0, stream>>>(h, bond_emb, intra_ei, intra_ea_ids, z);
        k_mlp_fused<<<FLATN / 128, 256, 0, stream>>>(
            gnn_W1 + (size_t)l * H * H, gnn_b1 + l * H,
            gnn_W2 + (size_t)l * H * H, gnn_b2 + l * H,
            z, node_ids, h);
    }

    k_tok<<<(S_SUB * H) / 256, 256, 0, stream>>>(h, htok);
    for (int l = 0; l < L_RO; ++l) {
        k_ro<<<N_TOTAL / RO_NPB, 256, 0, stream>>>(htok,
            ro_ln1_g + l * H, ro_ln1_b + l * H,
            ro_Wqkv + (size_t)l * H * 3 * H, ro_bqkv + l * 3 * H,
            ro_Wo + (size_t)l * H * H, ro_bo + l * H,
            ro_ln2_g + l * H, ro_ln2_b + l * H,
            ro_Wf1 + (size_t)l * H * FFN, ro_bf1 + l * FFN,
            ro_Wf2 + (size_t)l * FFN * H, ro_bf2 + l * H,
            log_probs, ht_alpha);
    }
    k_nodeemb<<<N_TOTAL, 128, 0, stream>>>(htok, out_ln_g, out_ln_b, nemb);
    k_out<<<B_GRAPHS, 128, 0, stream>>>(nemb, (float*)d_out);
}

// Round 4
// 1387.131 us; speedup vs baseline: 3.7910x; 1.8414x over previous
//
#include <hip/hip_runtime.h>
#include <hip/hip_bf16.h>
#include <math.h>

#define B_GRAPHS 32
#define NPG 128
#define N_TOTAL 4096
#define M_TOK 4
#define K_SUB 16
#define S_SUB 16384
#define FLATN 262144
#define H 128
#define NH 4
#define DH 32
#define STEPS 16
#define L_GNN 4
#define L_RO 2
#define EDGE_DIM 5
#define E_GLOB 32768
#define E_INTRA 524288
#define FFN 512

typedef __hip_bfloat16 bf16;
typedef __attribute__((ext_vector_type(8))) short s16x8;
typedef __attribute__((ext_vector_type(4))) float f32x4;

__device__ __forceinline__ float b2f(bf16 v) { return __bfloat162float(v); }
__device__ __forceinline__ bf16 f2b(float v) { return __float2bfloat16(v); }
__device__ __forceinline__ unsigned short f2bu(float v) {
    bf16 b = __float2bfloat16(v);
    return *(unsigned short*)&b;
}
__device__ __forceinline__ float rb2f(short u) {
    return __uint_as_float(((unsigned int)(unsigned short)u) << 16);
}

// ------------------------------------------------------------- utility ---

__global__ void k_zero4(float4* __restrict__ p, int n4) {
    int i = blockIdx.x * 256 + threadIdx.x;
    if (i < n4) p[i] = make_float4(0.f, 0.f, 0.f, 0.f);
}

__global__ void k_zeroi(int* __restrict__ p, int n) {
    int i = blockIdx.x * 256 + threadIdx.x;
    if (i < n) p[i] = 0;
}

// ------------------------------------------------------------ CSR build --
// histogram -> exclusive scan (block scan + top scan + add) -> scatter

__global__ void k_hist_edge(const int* __restrict__ iei, int* __restrict__ deg) {
    int e = blockIdx.x * 256 + threadIdx.x;
    if (e < E_INTRA) atomicAdd(&deg[iei[E_INTRA + e]], 1);
}

__global__ void k_hist_pool(const int* __restrict__ nid, int* __restrict__ degN) {
    int f = blockIdx.x * 256 + threadIdx.x;
    if (f < FLATN) atomicAdd(&degN[min(max(nid[f], 0), N_TOTAL - 1)], 1);
}

__global__ __launch_bounds__(256) void k_scan_blk(const int* __restrict__ in,
                                                  int* __restrict__ out,
                                                  int* __restrict__ bsum, int n) {
    __shared__ int s[256];
    int i = blockIdx.x * 256 + threadIdx.x;
    int v = (i < n) ? in[i] : 0;
    s[threadIdx.x] = v;
    __syncthreads();
    #pragma unroll
    for (int off = 1; off < 256; off <<= 1) {
        int t = (threadIdx.x >= off) ? s[threadIdx.x - off] : 0;
        __syncthreads();
        s[threadIdx.x] += t;
        __syncthreads();
    }
    if (i < n) out[i] = s[threadIdx.x] - v;         // exclusive
    if (threadIdx.x == 255) bsum[blockIdx.x] = s[255];
}

__global__ __launch_bounds__(256) void k_scan_top(int* __restrict__ bsum, int nb) {
    __shared__ int s[256];
    int base = threadIdx.x * 4;
    int v[4]; int loc = 0;
    #pragma unroll
    for (int j = 0; j < 4; ++j) {
        v[j] = (base + j < nb) ? bsum[base + j] : 0;
        loc += v[j];
    }
    s[threadIdx.x] = loc;
    __syncthreads();
    #pragma unroll
    for (int off = 1; off < 256; off <<= 1) {
        int t = (threadIdx.x >= off) ? s[threadIdx.x - off] : 0;
        __syncthreads();
        s[threadIdx.x] += t;
        __syncthreads();
    }
    int run = s[threadIdx.x] - loc;                 // exclusive of my chunk
    #pragma unroll
    for (int j = 0; j < 4; ++j) {
        if (base + j < nb) bsum[base + j] = run;
        run += v[j];
    }
}

__global__ void k_scan_add(int* __restrict__ out, const int* __restrict__ bsum,
                           int* __restrict__ cursor, int n) {
    int i = blockIdx.x * 256 + threadIdx.x;
    if (i < n) {
        int v = out[i] + bsum[i >> 8];
        out[i] = v;
        cursor[i] = v;
    }
}

__global__ void k_scatter_edge(const int* __restrict__ iei, const int* __restrict__ iea,
                               int* __restrict__ cursor, int* __restrict__ payload) {
    int e = blockIdx.x * 256 + threadIdx.x;
    if (e >= E_INTRA) return;
    int d = iei[E_INTRA + e];
    int pos = atomicAdd(&cursor[d], 1);
    payload[pos] = (iei[e] << 3) | iea[e];          // ea in 1..5 fits 3 bits
}

__global__ void k_scatter_pool(const int* __restrict__ nid, int* __restrict__ cursorN,
                               int* __restrict__ poolidx) {
    int f = blockIdx.x * 256 + threadIdx.x;
    if (f >= FLATN) return;
    int n = min(max(nid[f], 0), N_TOTAL - 1);
    int pos = atomicAdd(&cursorN[n], 1);
    poolidx[pos] = f;
}

// ---------------------------------------------------------------- RWSE ----

__global__ void k_adj(const int* __restrict__ ei, float* __restrict__ T) {
    int e = blockIdx.x * 256 + threadIdx.x;
    if (e >= E_GLOB) return;
    int s = ei[e], d = ei[E_GLOB + e];
    int g = s >> 7;
    atomicAdd(&T[(g * 128 + (s & 127)) * 128 + (d & 127)], 1.0f);
}

__global__ void k_rownorm(float* __restrict__ T) {
    int row = blockIdx.x * 4 + (threadIdx.x >> 6);
    int lane = threadIdx.x & 63;
    float* r = T + (size_t)row * 128;
    float v0 = r[lane], v1 = r[lane + 64];
    float s = v0 + v1;
    #pragma unroll
    for (int off = 32; off > 0; off >>= 1) s += __shfl_down(s, off);
    s = __shfl(s, 0);
    float inv = 1.0f / fmaxf(s, 1.0f);
    r[lane] = v0 * inv;
    r[lane + 64] = v1 * inv;
}

#define RW_BPG 32
#define RW_NPB (128 / RW_BPG)

__global__ __launch_bounds__(128) void k_rwse_chain(const float* __restrict__ T,
                                                    float* __restrict__ rwse) {
    __shared__ __align__(16) float Tl[128 * 128];
    __shared__ __align__(16) float rbuf[128];
    int g = blockIdx.x / RW_BPG, nb = blockIdx.x % RW_BPG;
    int tid = threadIdx.x;
    const float* Tg = T + (size_t)g * 16384;
    for (int idx = tid; idx < 16384; idx += 128) Tl[idx] = Tg[idx];
    __syncthreads();
    for (int ln = 0; ln < RW_NPB; ++ln) {
        int i = nb * RW_NPB + ln;
        float rv = Tl[i * 128 + tid];
        rbuf[tid] = rv;
        float* out = rwse + (size_t)(g * 128 + i) * STEPS;
        if (tid == i) out[0] = rv;
        __syncthreads();
        for (int s = 1; s < STEPS; ++s) {
            float acc = 0.f;
            const float4* r4 = (const float4*)rbuf;
            #pragma unroll
            for (int k4 = 0; k4 < 32; ++k4) {
                float4 rr = r4[k4];
                acc += rr.x * Tl[(k4 * 4 + 0) * 128 + tid]
                     + rr.y * Tl[(k4 * 4 + 1) * 128 + tid]
                     + rr.z * Tl[(k4 * 4 + 2) * 128 + tid]
                     + rr.w * Tl[(k4 * 4 + 3) * 128 + tid];
            }
            __syncthreads();
            rbuf[tid] = acc;
            if (tid == i) out[s] = acc;
            __syncthreads();
        }
    }
}

__global__ void k_rwse_head(const float* __restrict__ rwse, const float* __restrict__ rwse_W,
                            const float* __restrict__ rwse_b, const float* __restrict__ atom_emb,
                            const int* __restrict__ x_ids, float* __restrict__ base) {
    int idx = blockIdx.x * 256 + threadIdx.x;
    int n = idx >> 7, c = idx & 127;
    const float* r = rwse + (size_t)n * STEPS;
    float acc = rwse_b[c];
    #pragma unroll
    for (int s = 0; s < STEPS; ++s) acc += r[s] * rwse_W[s * H + c];
    acc = fmaxf(acc, 0.f);
    base[idx] = acc + atom_emb[x_ids[n] * H + c];
}

__global__ void k_hinit(const float* __restrict__ base, const int* __restrict__ node_ids,
                        bf16* __restrict__ h) {
    int idx = blockIdx.x * 256 + threadIdx.x;
    int f = idx >> 7, c = idx & 127;
    int nidv = node_ids[f];
    int n = min(max(nidv, 0), N_TOTAL - 1);
    float v = base[n * H + c];
    if (nidv < 0) v = 0.f;
    h[idx] = f2b(v);
}

// ---------------------------------------------------------------- GNN -----

// gpool[n] = sum of h rows mapping to n (h invalid rows are kept zero)
__global__ void k_pool_csr(const bf16* __restrict__ h, const int* __restrict__ rpN,
                           const int* __restrict__ degN, const int* __restrict__ poolidx,
                           float* __restrict__ gpool) {
    int idx = blockIdx.x * 256 + threadIdx.x;   // n*128 + c
    int n = idx >> 7, c = idx & 127;
    float acc = 0.f;
    int beg = rpN[n], end = beg + degN[n];
    for (int j = beg; j < end; ++j) {
        int f = poolidx[j];
        acc += b2f(h[(size_t)f * H + c]);
    }
    gpool[idx] = acc;
}

__global__ void k_gagg(const float* __restrict__ gpool, const float* __restrict__ bond_emb,
                       const int* __restrict__ ei, const int* __restrict__ ea_ids,
                       float* __restrict__ gagg) {
    int idx = blockIdx.x * 256 + threadIdx.x;
    int e = idx >> 7, c = idx & 127;
    int s = ei[e], d = ei[E_GLOB + e];
    float v = fmaxf(gpool[s * H + c] + bond_emb[(ea_ids[e] - 1) * H + c], 0.f);
    atomicAdd(&gagg[d * H + c], v);
}

// z[f] = h[f] + gagg[nid[f]] + sum_e relu(h[src_e] + ea_e), written bf16
__global__ void k_aggz(const bf16* __restrict__ h, const float* __restrict__ gagg,
                       const float* __restrict__ bond_emb, const int* __restrict__ node_ids,
                       const int* __restrict__ rp, const int* __restrict__ deg,
                       const int* __restrict__ payload, bf16* __restrict__ z) {
    int idx = blockIdx.x * 256 + threadIdx.x;   // f*16 + c8blk
    int f = idx >> 4, c8 = (idx & 15) << 3;
    int n = min(max(node_ids[f], 0), N_TOTAL - 1);
    float acc[8];
    s16x8 hv = *(const s16x8*)(h + (size_t)f * H + c8);
    const float* gg = gagg + (size_t)n * H + c8;
    #pragma unroll
    for (int j = 0; j < 8; ++j) acc[j] = rb2f(hv[j]) + gg[j];
    int beg = rp[f], end = beg + deg[f];
    for (int e = beg; e < end; ++e) {
        int p = payload[e];
        int src = p >> 3, ea = (p & 7) - 1;
        s16x8 hs = *(const s16x8*)(h + (size_t)src * H + c8);
        const float* be = bond_emb + ea * H + c8;
        #pragma unroll
        for (int j = 0; j < 8; ++j) acc[j] += fmaxf(rb2f(hs[j]) + be[j], 0.f);
    }
    s16x8 o;
    #pragma unroll
    for (int j = 0; j < 8; ++j) o[j] = (short)f2bu(acc[j]);
    *(s16x8*)(z + (size_t)f * H + c8) = o;
}

// Fused GINE MLP: h = (h + W2@relu(W1@z + b1) + b2) * valid, bf16 MFMA.
#define LDW 136   // LDS row stride (shorts): 272B, 16B-aligned

__global__ __launch_bounds__(256) void k_mlp_fused(
    const float* __restrict__ W1, const float* __restrict__ b1,
    const float* __restrict__ W2, const float* __restrict__ b2,
    const bf16* __restrict__ z, const int* __restrict__ node_ids,
    bf16* __restrict__ h) {
    __shared__ unsigned short zt[128][LDW];
    __shared__ unsigned short mt[128][LDW];
    __shared__ float validf[128];

    int tid = threadIdx.x;
    int w = tid >> 6;
    int l = tid & 63;
    int brow0 = blockIdx.x * 128;

    // --- stage z tile (bf16 copy) + valid flags ---
    {
        int r = tid >> 1, c0 = (tid & 1) * 64;
        const s16x8* zr = (const s16x8*)(z + (size_t)(brow0 + r) * H + c0);
        #pragma unroll
        for (int i = 0; i < 8; ++i)
            *(s16x8*)&zt[r][c0 + i * 8] = zr[i];
        if (tid < 128) validf[tid] = (node_ids[brow0 + tid] >= 0) ? 1.f : 0.f;
    }

    // --- W1/W2 fragments (fp32 -> bf16), L2-resident ---
    s16x8 bw1[2][4], bw2[2][4];
    float b1c[2], b2c[2];
    #pragma unroll
    for (int nt = 0; nt < 2; ++nt) {
        int col = w * 32 + nt * 16 + (l & 15);
        b1c[nt] = b1[col];
        b2c[nt] = b2[col];
        #pragma unroll
        for (int kt = 0; kt < 4; ++kt) {
            int k0 = kt * 32 + (l >> 4) * 8;
            #pragma unroll
            for (int j = 0; j < 8; ++j) {
                bw1[nt][kt][j] = (short)f2bu(W1[(size_t)(k0 + j) * H + col]);
                bw2[nt][kt][j] = (short)f2bu(W2[(size_t)(k0 + j) * H + col]);
            }
        }
    }
    __syncthreads();

    // --- GEMM1: mid = relu(z @ W1 + b1) ---
    f32x4 acc[8][2];
    #pragma unroll
    for (int mt_i = 0; mt_i < 8; ++mt_i)
        #pragma unroll
        for (int nt = 0; nt < 2; ++nt)
            acc[mt_i][nt] = f32x4{0.f, 0.f, 0.f, 0.f};
    #pragma unroll
    for (int kt = 0; kt < 4; ++kt) {
        #pragma unroll
        for (int mt_i = 0; mt_i < 8; ++mt_i) {
            s16x8 a = *(const s16x8*)&zt[mt_i * 16 + (l & 15)][kt * 32 + (l >> 4) * 8];
            acc[mt_i][0] = __builtin_amdgcn_mfma_f32_16x16x32_bf16(a, bw1[0][kt], acc[mt_i][0], 0, 0, 0);
            acc[mt_i][1] = __builtin_amdgcn_mfma_f32_16x16x32_bf16(a, bw1[1][kt], acc[mt_i][1], 0, 0, 0);
        }
    }
    #pragma unroll
    for (int mt_i = 0; mt_i < 8; ++mt_i) {
        #pragma unroll
        for (int nt = 0; nt < 2; ++nt) {
            int col = w * 32 + nt * 16 + (l & 15);
            #pragma unroll
            for (int r = 0; r < 4; ++r) {
                int row = mt_i * 16 + (l >> 4) * 4 + r;
                mt[row][col] = f2bu(fmaxf(acc[mt_i][nt][r] + b1c[nt], 0.f));
            }
        }
    }
    __syncthreads();

    // --- GEMM2: out = mid @ W2 ---
    #pragma unroll
    for (int mt_i = 0; mt_i < 8; ++mt_i)
        #pragma unroll
        for (int nt = 0; nt < 2; ++nt)
            acc[mt_i][nt] = f32x4{0.f, 0.f, 0.f, 0.f};
    #pragma unroll
    for (int kt = 0; kt < 4; ++kt) {
        #pragma unroll
        for (int mt_i = 0; mt_i < 8; ++mt_i) {
            s16x8 a = *(const s16x8*)&mt[mt_i * 16 + (l & 15)][kt * 32 + (l >> 4) * 8];
            acc[mt_i][0] = __builtin_amdgcn_mfma_f32_16x16x32_bf16(a, bw2[0][kt], acc[mt_i][0], 0, 0, 0);
            acc[mt_i][1] = __builtin_amdgcn_mfma_f32_16x16x32_bf16(a, bw2[1][kt], acc[mt_i][1], 0, 0, 0);
        }
    }
    #pragma unroll
    for (int mt_i = 0; mt_i < 8; ++mt_i) {
        #pragma unroll
        for (int nt = 0; nt < 2; ++nt) {
            int col = w * 32 + nt * 16 + (l & 15);
            #pragma unroll
            for (int r = 0; r < 4; ++r) {
                int row = mt_i * 16 + (l >> 4) * 4 + r;
                size_t g = (size_t)(brow0 + row) * H + col;
                float hv = b2f(h[g]);
                h[g] = f2b((hv + acc[mt_i][nt][r] + b2c[nt]) * validf[row]);
            }
        }
    }
}

// ------------------------------------------------------------- Readout ---

__global__ void k_tok(const bf16* __restrict__ h, float* __restrict__ htok) {
    int idx = blockIdx.x * 256 + threadIdx.x;
    int s = idx >> 7, c = idx & 127;
    htok[idx] = b2f(h[(size_t)s * K_SUB * H + c]);
}

#define XT_STRIDE 132
#define QKV_STRIDE 385
#define RO_NPB 4

__device__ __forceinline__ void ln16(const float* __restrict__ x, float* __restrict__ y,
                                     const float* __restrict__ g, const float* __restrict__ b,
                                     int tid) {
    int t = tid >> 4, sub = tid & 15;
    const float* xr = x + t * XT_STRIDE + sub * 8;
    float4 a = *(const float4*)xr;
    float4 bq = *(const float4*)(xr + 4);
    float s  = a.x + a.y + a.z + a.w + bq.x + bq.y + bq.z + bq.w;
    float ss = a.x * a.x + a.y * a.y + a.z * a.z + a.w * a.w
             + bq.x * bq.x + bq.y * bq.y + bq.z * bq.z + bq.w * bq.w;
    #pragma unroll
    for (int m = 1; m < 16; m <<= 1) { s += __shfl_xor(s, m); ss += __shfl_xor(ss, m); }
    float mu = s * (1.f / 128.f);
    float var = ss * (1.f / 128.f) - mu * mu;
    float inv = rsqrtf(var + 1e-5f);
    float* yr = y + t * XT_STRIDE + sub * 8;
    const float* gp = g + sub * 8;
    const float* bp = b + sub * 8;
    float xv[8] = {a.x, a.y, a.z, a.w, bq.x, bq.y, bq.z, bq.w};
    #pragma unroll
    for (int i = 0; i < 8; ++i) yr[i] = (xv[i] - mu) * inv * gp[i] + bp[i];
}

__global__ __launch_bounds__(256) void k_ro(
    float* __restrict__ htok,
    const float* __restrict__ g1, const float* __restrict__ b1,
    const float* __restrict__ Wqkv, const float* __restrict__ bqkv,
    const float* __restrict__ Wo, const float* __restrict__ bo,
    const float* __restrict__ g2, const float* __restrict__ b2,
    const float* __restrict__ Wf1, const float* __restrict__ bf1,
    const float* __restrict__ Wf2, const float* __restrict__ bf2,
    const float* __restrict__ log_probs, const float* __restrict__ alpha_p) {
    __shared__ __align__(16) float xt[16 * XT_STRIDE];
    __shared__ __align__(16) float xn[16 * XT_STRIDE];
    __shared__ __align__(16) float buf[16 * FFN];
    __shared__ float pmat[256];
    __shared__ float lpv[16];
    int tid = threadIdx.x;
    int node0 = blockIdx.x * RO_NPB;
    float alpha = alpha_p[0];

    for (int i = tid; i < 16 * 128; i += 256) {
        int t = i >> 7, c = i & 127;
        xt[t * XT_STRIDE + c] = htok[(size_t)(node0 * 4 + t) * H + c];
    }
    if (tid < 16) {
        float lp = log_probs[node0 * 4 + tid];
        lpv[tid] = isfinite(lp) ? lp : 0.f;
    }
    __syncthreads();

    ln16(xt, xn, g1, b1, tid);
    __syncthreads();

    for (int cb = 0; cb < 2; ++cb) {
        int col = cb * 256 + tid;
        if (col < 384) {
            float acc[16];
            #pragma unroll
            for (int t = 0; t < 16; ++t) acc[t] = 0.f;
            for (int k4 = 0; k4 < 32; ++k4) {
                float w0 = Wqkv[(k4 * 4 + 0) * 384 + col];
                float w1 = Wqkv[(k4 * 4 + 1) * 384 + col];
                float w2 = Wqkv[(k4 * 4 + 2) * 384 + col];
                float w3 = Wqkv[(k4 * 4 + 3) * 384 + col];
                #pragma unroll
                for (int t = 0; t < 16; ++t) {
                    float4 xv = *(const float4*)&xn[t * XT_STRIDE + k4 * 4];
                    acc[t] += xv.x * w0 + xv.y * w1 + xv.z * w2 + xv.w * w3;
                }
            }
            float bb = bqkv[col];
            #pragma unroll
            for (int t = 0; t < 16; ++t) buf[t * QKV_STRIDE + col] = acc[t] + bb;
        }
    }
    __syncthreads();

    {
        int ln = tid >> 6, hh = (tid >> 4) & 3, ii = (tid >> 2) & 3, jj = tid & 3;
        const float* q = buf + (ln * 4 + ii) * QKV_STRIDE + hh * 32;
        const float* kk = buf + (ln * 4 + jj) * QKV_STRIDE + 128 + hh * 32;
        float sc = 0.f;
        #pragma unroll
        for (int d = 0; d < 32; ++d) sc += q[d] * kk[d];
        sc = sc * 0.17677669529663689f + alpha * lpv[ln * 4 + jj];
        float mx = fmaxf(sc, __shfl_xor(sc, 1));
        mx = fmaxf(mx, __shfl_xor(mx, 2));
        float e = expf(sc - mx);
        float se = e + __shfl_xor(e, 1);
        se += __shfl_xor(se, 2);
        pmat[tid] = e / se;
    }
    __syncthreads();

    {
        int t = tid >> 4, sub = tid & 15;
        int ln = t >> 2, ii = t & 3;
        #pragma unroll
        for (int q8 = 0; q8 < 8; ++q8) {
            int c = sub * 8 + q8;
            int hh = c >> 5;
            const float* p = pmat + ((ln * 4 + hh) * 4 + ii) * 4;
            float acc = p[0] * buf[(ln * 4 + 0) * QKV_STRIDE + 256 + c]
                      + p[1] * buf[(ln * 4 + 1) * QKV_STRIDE + 256 + c]
                      + p[2] * buf[(ln * 4 + 2) * QKV_STRIDE + 256 + c]
                      + p[3] * buf[(ln * 4 + 3) * QKV_STRIDE + 256 + c];
            xn[t * XT_STRIDE + c] = acc;
        }
    }
    __syncthreads();

    {
        int c = tid & 127, tg = tid >> 7;
        float acc[8];
        #pragma unroll
        for (int t8 = 0; t8 < 8; ++t8) acc[t8] = 0.f;
        for (int k4 = 0; k4 < 32; ++k4) {
            float w0 = Wo[(k4 * 4 + 0) * H + c];
            float w1 = Wo[(k4 * 4 + 1) * H + c];
            float w2 = Wo[(k4 * 4 + 2) * H + c];
            float w3 = Wo[(k4 * 4 + 3) * H + c];
            #pragma unroll
            for (int t8 = 0; t8 < 8; ++t8) {
                float4 xv = *(const float4*)&xn[(tg * 8 + t8) * XT_STRIDE + k4 * 4];
                acc[t8] += xv.x * w0 + xv.y * w1 + xv.z * w2 + xv.w * w3;
            }
        }
        float bb = bo[c];
        #pragma unroll
        for (int t8 = 0; t8 < 8; ++t8) xt[(tg * 8 + t8) * XT_STRIDE + c] += acc[t8] + bb;
    }
    __syncthreads();

    ln16(xt, xn, g2, b2, tid);
    __syncthreads();

    for (int cb = 0; cb < 2; ++cb) {
        int col = cb * 256 + tid;
        float acc[16];
        #pragma unroll
        for (int t = 0; t < 16; ++t) acc[t] = 0.f;
        for (int k4 = 0; k4 < 32; ++k4) {
            float w0 = Wf1[(k4 * 4 + 0) * FFN + col];
            float w1 = Wf1[(k4 * 4 + 1) * FFN + col];
            float w2 = Wf1[(k4 * 4 + 2) * FFN + col];
            float w3 = Wf1[(k4 * 4 + 3) * FFN + col];
            #pragma unroll
            for (int t = 0; t < 16; ++t) {
                float4 xv = *(const float4*)&xn[t * XT_STRIDE + k4 * 4];
                acc[t] += xv.x * w0 + xv.y * w1 + xv.z * w2 + xv.w * w3;
            }
        }
        float bb = bf1[col];
        #pragma unroll
        for (int t = 0; t < 16; ++t) {
            float v = acc[t] + bb;
            buf[t * FFN + col] = v * 0.5f * (1.f + erff(v * 0.70710678118654752f));
        }
    }
    __syncthreads();

    {
        int c = tid & 127, tg = tid >> 7;
        float acc[8];
        #pragma unroll
        for (int t8 = 0; t8 < 8; ++t8) acc[t8] = 0.f;
        for (int k4 = 0; k4 < 128; ++k4) {
            float w0 = Wf2[(k4 * 4 + 0) * H + c];
            float w1 = Wf2[(k4 * 4 + 1) * H + c];
            float w2 = Wf2[(k4 * 4 + 2) * H + c];
            float w3 = Wf2[(k4 * 4 + 3) * H + c];
            #pragma unroll
            for (int t8 = 0; t8 < 8; ++t8) {
                float4 mv = *(const float4*)&buf[(tg * 8 + t8) * FFN + k4 * 4];
                acc[t8] += mv.x * w0 + mv.y * w1 + mv.z * w2 + mv.w * w3;
            }
        }
        float bb = bf2[c];
        #pragma unroll
        for (int t8 = 0; t8 < 8; ++t8) xt[(tg * 8 + t8) * XT_STRIDE + c] += acc[t8] + bb;
    }
    __syncthreads();

    for (int i = tid; i < 16 * 128; i += 256) {
        int t = i >> 7, c = i & 127;
        htok[(size_t)(node0 * 4 + t) * H + c] = xt[t * XT_STRIDE + c];
    }
}

__global__ __launch_bounds__(128) void k_nodeemb(const float* __restrict__ htok,
                                                 const float* __restrict__ og,
                                                 const float* __restrict__ ob,
                                                 float* __restrict__ nemb) {
    int n = blockIdx.x, c = threadIdx.x;
    const float* hr = htok + (size_t)n * 4 * H;
    float v = 0.25f * (hr[c] + hr[H + c] + hr[2 * H + c] + hr[3 * H + c]);
    float s = v, ss = v * v;
    #pragma unroll
    for (int m = 1; m < 64; m <<= 1) { s += __shfl_xor(s, m); ss += __shfl_xor(ss, m); }
    __shared__ float red[4];
    if ((threadIdx.x & 63) == 0) {
        red[(threadIdx.x >> 6) * 2] = s;
        red[(threadIdx.x >> 6) * 2 + 1] = ss;
    }
    __syncthreads();
    s = red[0] + red[2];
    ss = red[1] + red[3];
    float mu = s * (1.f / 128.f);
    float var = ss * (1.f / 128.f) - mu * mu;
    float inv = rsqrtf(var + 1e-5f);
    nemb[(size_t)n * H + c] = (v - mu) * inv * og[c] + ob[c];
}

__global__ __launch_bounds__(128) void k_out(const float* __restrict__ nemb,
                                             float* __restrict__ out) {
    int g = blockIdx.x, c = threadIdx.x;
    float acc = 0.f;
    for (int i = 0; i < 128; ++i) acc += nemb[(size_t)(g * 128 + i) * H + c];
    out[g * H + c] = acc;
}

// ------------------------------------------------------------- launch ----

extern "C" void kernel_launch(void* const* d_in, const int* in_sizes, int n_in,
                              void* d_out, int out_size, void* d_ws, size_t ws_size,
                              hipStream_t stream) {
    (void)in_sizes; (void)n_in; (void)out_size;
    const int* edge_index    = (const int*)d_in[0];
    const int* intra_ei      = (const int*)d_in[1];
    const int* edge_attr_ids = (const int*)d_in[2];
    const int* intra_ea_ids  = (const int*)d_in[3];
    const int* node_ids      = (const int*)d_in[4];
    const int* x_ids         = (const int*)d_in[5];
    const float* log_probs   = (const float*)d_in[7];
    const float* atom_emb    = (const float*)d_in[8];
    const float* bond_emb    = (const float*)d_in[9];
    const float* rwse_W      = (const float*)d_in[10];
    const float* rwse_b      = (const float*)d_in[11];
    const float* gnn_W1      = (const float*)d_in[12];
    const float* gnn_b1      = (const float*)d_in[13];
    const float* gnn_W2      = (const float*)d_in[14];
    const float* gnn_b2      = (const float*)d_in[15];
    const float* ro_ln1_g    = (const float*)d_in[16];
    const float* ro_ln1_b    = (const float*)d_in[17];
    const float* ro_Wqkv     = (const float*)d_in[18];
    const float* ro_bqkv     = (const float*)d_in[19];
    const float* ro_Wo       = (const float*)d_in[20];
    const float* ro_bo       = (const float*)d_in[21];
    const float* ro_ln2_g    = (const float*)d_in[22];
    const float* ro_ln2_b    = (const float*)d_in[23];
    const float* ro_Wf1      = (const float*)d_in[24];
    const float* ro_bf1      = (const float*)d_in[25];
    const float* ro_Wf2      = (const float*)d_in[26];
    const float* ro_bf2      = (const float*)d_in[27];
    const float* out_ln_g    = (const float*)d_in[28];
    const float* out_ln_b    = (const float*)d_in[29];
    const float* ht_alpha    = (const float*)d_in[30];

    char* ws = (char*)d_ws;
    size_t off = 0;
    auto alloc = [&](size_t nbytes) {
        char* p = ws + off;
        off += (nbytes + 255) & ~(size_t)255;
        return p;
    };
    float* T       = (float*)alloc((size_t)B_GRAPHS * 128 * 128 * 4);
    float* rwse    = (float*)alloc((size_t)N_TOTAL * STEPS * 4);
    float* base    = (float*)alloc((size_t)N_TOTAL * H * 4);
    float* gbuf    = (float*)alloc((size_t)2 * N_TOTAL * H * 4);
    float* htok    = (float*)alloc((size_t)S_SUB * H * 4);
    float* nemb    = (float*)alloc((size_t)N_TOTAL * H * 4);
    bf16*  z       = (bf16*)alloc((size_t)FLATN * H * 2);
    bf16*  h       = (bf16*)alloc((size_t)FLATN * H * 2);
    int*   deg     = (int*)alloc((size_t)FLATN * 4);
    int*   rp      = (int*)alloc((size_t)FLATN * 4);
    int*   cursor  = (int*)alloc((size_t)FLATN * 4);
    int*   payload = (int*)alloc((size_t)E_INTRA * 4);
    int*   degN    = (int*)alloc((size_t)N_TOTAL * 4);
    int*   rpN     = (int*)alloc((size_t)N_TOTAL * 4);
    int*   cursorN = (int*)alloc((size_t)N_TOTAL * 4);
    int*   poolidx = (int*)alloc((size_t)FLATN * 4);
    int*   bsum    = (int*)alloc(1024 * 4);
    int*   bsumN   = (int*)alloc(16 * 4);
    float* gpool   = gbuf;
    float* gagg    = gbuf + (size_t)N_TOTAL * H;

    if (off > ws_size) return;

    // ---- CSR build (loop-invariant, once per launch) ----
    k_zeroi<<<FLATN / 256, 256, 0, stream>>>(deg, FLATN);
    k_zeroi<<<N_TOTAL / 256, 256, 0, stream>>>(degN, N_TOTAL);
    k_hist_edge<<<E_INTRA / 256, 256, 0, stream>>>(intra_ei, deg);
    k_hist_pool<<<FLATN / 256, 256, 0, stream>>>(node_ids, degN);
    k_scan_blk<<<FLATN / 256, 256, 0, stream>>>(deg, rp, bsum, FLATN);
    k_scan_top<<<1, 256, 0, stream>>>(bsum, FLATN / 256);
    k_scan_add<<<FLATN / 256, 256, 0, stream>>>(rp, bsum, cursor, FLATN);
    k_scan_blk<<<N_TOTAL / 256, 256, 0, stream>>>(degN, rpN, bsumN, N_TOTAL);
    k_scan_top<<<1, 256, 0, stream>>>(bsumN, N_TOTAL / 256);
    k_scan_add<<<N_TOTAL / 256, 256, 0, stream>>>(rpN, bsumN, cursorN, N_TOTAL);
    k_scatter_edge<<<E_INTRA / 256, 256, 0, stream>>>(intra_ei, intra_ea_ids, cursor, payload);
    k_scatter_pool<<<FLATN / 256, 256, 0, stream>>>(node_ids, cursorN, poolidx);

    // ---- RWSE ----
    k_zero4<<<(B_GRAPHS * 128 * 128 / 4 + 255) / 256, 256, 0, stream>>>((float4*)T, B_GRAPHS * 128 * 128 / 4);
    k_adj<<<E_GLOB / 256, 256, 0, stream>>>(edge_index, T);
    k_rownorm<<<(B_GRAPHS * 128) / 4, 256, 0, stream>>>(T);
    k_rwse_chain<<<B_GRAPHS * RW_BPG, 128, 0, stream>>>(T, rwse);
    k_rwse_head<<<(N_TOTAL * H) / 256, 256, 0, stream>>>(rwse, rwse_W, rwse_b, atom_emb, x_ids, base);
    k_hinit<<<(FLATN * H) / 256, 256, 0, stream>>>(base, node_ids, h);

    // ---- GNN layers ----
    for (int l = 0; l < L_GNN; ++l) {
        k_zero4<<<(N_TOTAL * H / 4 + 255) / 256, 256, 0, stream>>>((float4*)gagg, N_TOTAL * H / 4);
        k_pool_csr<<<(N_TOTAL * H) / 256, 256, 0, stream>>>(h, rpN, degN, poolidx, gpool);
        k_gagg<<<(E_GLOB * H) / 256, 256, 0, stream>>>(gpool, bond_emb, edge_index, edge_attr_ids, gagg);
        k_aggz<<<(FLATN * 16) / 256, 256, 0, stream>>>(h, gagg, bond_emb, node_ids, rp, deg, payload, z);
        k_mlp_fused<<<FLATN / 128, 256, 0, stream>>>(
            gnn_W1 + (size_t)l * H * H, gnn_b1 + l * H,
            gnn_W2 + (size_t)l * H * H, gnn_b2 + l * H,
            z, node_ids, h);
    }

    // ---- Readout ----
    k_tok<<<(S_SUB * H) / 256, 256, 0, stream>>>(h, htok);
    for (int l = 0; l < L_RO; ++l) {
        k_ro<<<N_TOTAL / RO_NPB, 256, 0, stream>>>(htok,
            ro_ln1_g + l * H, ro_ln1_b + l * H,
            ro_Wqkv + (size_t)l * H * 3 * H, ro_bqkv + l * 3 * H,
            ro_Wo + (size_t)l * H * H, ro_bo + l * H,
            ro_ln2_g + l * H, ro_ln2_b + l * H,
            ro_Wf1 + (size_t)l * H * FFN, ro_bf1 + l * FFN,
            ro_Wf2 + (size_t)l * FFN * H, ro_bf2 + l * H,
            log_probs, ht_alpha);
    }
    k_nodeemb<<<N_TOTAL, 128, 0, stream>>>(htok, out_ln_g, out_ln_b, nemb);
    k_out<<<B_GRAPHS, 128, 0, stream>>>(nemb, (float*)d_out);
}

// Round 5
// 1143.544 us; speedup vs baseline: 4.5985x; 1.2130x over previous
//
#include <hip/hip_runtime.h>
#include <hip/hip_bf16.h>
#include <math.h>

#define B_GRAPHS 32
#define NPG 128
#define N_TOTAL 4096
#define M_TOK 4
#define K_SUB 16
#define S_SUB 16384
#define FLATN 262144
#define H 128
#define NH 4
#define DH 32
#define STEPS 16
#define L_GNN 4
#define L_RO 2
#define EDGE_DIM 5
#define E_GLOB 32768
#define E_INTRA 524288
#define FFN 512

typedef __hip_bfloat16 bf16;
typedef __attribute__((ext_vector_type(8))) short s16x8;
typedef __attribute__((ext_vector_type(4))) float f32x4;

__device__ __forceinline__ float b2f(bf16 v) { return __bfloat162float(v); }
__device__ __forceinline__ bf16 f2b(float v) { return __float2bfloat16(v); }
__device__ __forceinline__ unsigned short f2bu(float v) {
    bf16 b = __float2bfloat16(v);
    return *(unsigned short*)&b;
}
__device__ __forceinline__ float rb2f(short u) {
    return __uint_as_float(((unsigned int)(unsigned short)u) << 16);
}

// ------------------------------------------------------------- utility ---

__global__ void k_zero4(float4* __restrict__ p, int n4) {
    int i = blockIdx.x * 256 + threadIdx.x;
    if (i < n4) p[i] = make_float4(0.f, 0.f, 0.f, 0.f);
}

__global__ void k_zeroi(int* __restrict__ p, int n) {
    int i = blockIdx.x * 256 + threadIdx.x;
    if (i < n) p[i] = 0;
}

// ------------------------------------------------------------ CSR build --

__global__ void k_hist_edge(const int* __restrict__ iei, int* __restrict__ deg) {
    int e = blockIdx.x * 256 + threadIdx.x;
    if (e < E_INTRA) atomicAdd(&deg[iei[E_INTRA + e]], 1);
}

__global__ void k_hist_pool(const int* __restrict__ nid, int* __restrict__ degN) {
    int f = blockIdx.x * 256 + threadIdx.x;
    if (f < FLATN) atomicAdd(&degN[min(max(nid[f], 0), N_TOTAL - 1)], 1);
}

__global__ __launch_bounds__(256) void k_scan_blk(const int* __restrict__ in,
                                                  int* __restrict__ out,
                                                  int* __restrict__ bsum, int n) {
    __shared__ int s[256];
    int i = blockIdx.x * 256 + threadIdx.x;
    int v = (i < n) ? in[i] : 0;
    s[threadIdx.x] = v;
    __syncthreads();
    #pragma unroll
    for (int off = 1; off < 256; off <<= 1) {
        int t = (threadIdx.x >= off) ? s[threadIdx.x - off] : 0;
        __syncthreads();
        s[threadIdx.x] += t;
        __syncthreads();
    }
    if (i < n) out[i] = s[threadIdx.x] - v;
    if (threadIdx.x == 255) bsum[blockIdx.x] = s[255];
}

__global__ __launch_bounds__(256) void k_scan_top(int* __restrict__ bsum, int nb) {
    __shared__ int s[256];
    int base = threadIdx.x * 4;
    int v[4]; int loc = 0;
    #pragma unroll
    for (int j = 0; j < 4; ++j) {
        v[j] = (base + j < nb) ? bsum[base + j] : 0;
        loc += v[j];
    }
    s[threadIdx.x] = loc;
    __syncthreads();
    #pragma unroll
    for (int off = 1; off < 256; off <<= 1) {
        int t = (threadIdx.x >= off) ? s[threadIdx.x - off] : 0;
        __syncthreads();
        s[threadIdx.x] += t;
        __syncthreads();
    }
    int run = s[threadIdx.x] - loc;
    #pragma unroll
    for (int j = 0; j < 4; ++j) {
        if (base + j < nb) bsum[base + j] = run;
        run += v[j];
    }
}

__global__ void k_scan_add(int* __restrict__ out, const int* __restrict__ bsum,
                           int* __restrict__ cursor, int n) {
    int i = blockIdx.x * 256 + threadIdx.x;
    if (i < n) {
        int v = out[i] + bsum[i >> 8];
        out[i] = v;
        cursor[i] = v;
    }
}

__global__ void k_scatter_edge(const int* __restrict__ iei, const int* __restrict__ iea,
                               int* __restrict__ cursor, int* __restrict__ payload) {
    int e = blockIdx.x * 256 + threadIdx.x;
    if (e >= E_INTRA) return;
    int d = iei[E_INTRA + e];
    int pos = atomicAdd(&cursor[d], 1);
    payload[pos] = (iei[e] << 3) | iea[e];
}

__global__ void k_scatter_pool(const int* __restrict__ nid, int* __restrict__ cursorN,
                               int* __restrict__ poolidx) {
    int f = blockIdx.x * 256 + threadIdx.x;
    if (f >= FLATN) return;
    int n = min(max(nid[f], 0), N_TOTAL - 1);
    int pos = atomicAdd(&cursorN[n], 1);
    poolidx[pos] = f;
}

// ---------------------------------------------------------------- RWSE ----

__global__ void k_adj(const int* __restrict__ ei, float* __restrict__ T) {
    int e = blockIdx.x * 256 + threadIdx.x;
    if (e >= E_GLOB) return;
    int s = ei[e], d = ei[E_GLOB + e];
    int g = s >> 7;
    atomicAdd(&T[(g * 128 + (s & 127)) * 128 + (d & 127)], 1.0f);
}

__global__ void k_rownorm(float* __restrict__ T) {
    int row = blockIdx.x * 4 + (threadIdx.x >> 6);
    int lane = threadIdx.x & 63;
    float* r = T + (size_t)row * 128;
    float v0 = r[lane], v1 = r[lane + 64];
    float s = v0 + v1;
    #pragma unroll
    for (int off = 32; off > 0; off >>= 1) s += __shfl_down(s, off);
    s = __shfl(s, 0);
    float inv = 1.0f / fmaxf(s, 1.0f);
    r[lane] = v0 * inv;
    r[lane + 64] = v1 * inv;
}

#define RW_BPG 32
#define RW_NPB (128 / RW_BPG)

__global__ __launch_bounds__(128) void k_rwse_chain(const float* __restrict__ T,
                                                    float* __restrict__ rwse) {
    __shared__ __align__(16) float Tl[128 * 128];
    __shared__ __align__(16) float rbuf[128];
    int g = blockIdx.x / RW_BPG, nb = blockIdx.x % RW_BPG;
    int tid = threadIdx.x;
    const float* Tg = T + (size_t)g * 16384;
    for (int idx = tid; idx < 16384; idx += 128) Tl[idx] = Tg[idx];
    __syncthreads();
    for (int ln = 0; ln < RW_NPB; ++ln) {
        int i = nb * RW_NPB + ln;
        float rv = Tl[i * 128 + tid];
        rbuf[tid] = rv;
        float* out = rwse + (size_t)(g * 128 + i) * STEPS;
        if (tid == i) out[0] = rv;
        __syncthreads();
        for (int s = 1; s < STEPS; ++s) {
            float acc = 0.f;
            const float4* r4 = (const float4*)rbuf;
            #pragma unroll
            for (int k4 = 0; k4 < 32; ++k4) {
                float4 rr = r4[k4];
                acc += rr.x * Tl[(k4 * 4 + 0) * 128 + tid]
                     + rr.y * Tl[(k4 * 4 + 1) * 128 + tid]
                     + rr.z * Tl[(k4 * 4 + 2) * 128 + tid]
                     + rr.w * Tl[(k4 * 4 + 3) * 128 + tid];
            }
            __syncthreads();
            rbuf[tid] = acc;
            if (tid == i) out[s] = acc;
            __syncthreads();
        }
    }
}

__global__ void k_rwse_head(const float* __restrict__ rwse, const float* __restrict__ rwse_W,
                            const float* __restrict__ rwse_b, const float* __restrict__ atom_emb,
                            const int* __restrict__ x_ids, float* __restrict__ base) {
    int idx = blockIdx.x * 256 + threadIdx.x;
    int n = idx >> 7, c = idx & 127;
    const float* r = rwse + (size_t)n * STEPS;
    float acc = rwse_b[c];
    #pragma unroll
    for (int s = 0; s < STEPS; ++s) acc += r[s] * rwse_W[s * H + c];
    acc = fmaxf(acc, 0.f);
    base[idx] = acc + atom_emb[x_ids[n] * H + c];
}

__global__ void k_hinit(const float* __restrict__ base, const int* __restrict__ node_ids,
                        bf16* __restrict__ h) {
    int idx = blockIdx.x * 256 + threadIdx.x;
    int f = idx >> 7, c = idx & 127;
    int nidv = node_ids[f];
    int n = min(max(nidv, 0), N_TOTAL - 1);
    float v = base[n * H + c];
    if (nidv < 0) v = 0.f;
    h[idx] = f2b(v);
}

// ---------------------------------------------------------------- GNN -----

__global__ void k_pool_csr(const bf16* __restrict__ h, const int* __restrict__ rpN,
                           const int* __restrict__ degN, const int* __restrict__ poolidx,
                           float* __restrict__ gpool) {
    int idx = blockIdx.x * 256 + threadIdx.x;
    int n = idx >> 7, c = idx & 127;
    float acc = 0.f;
    int beg = rpN[n], end = beg + degN[n];
    for (int j = beg; j < end; ++j) {
        int f = poolidx[j];
        acc += b2f(h[(size_t)f * H + c]);
    }
    gpool[idx] = acc;
}

__global__ void k_gagg(const float* __restrict__ gpool, const float* __restrict__ bond_emb,
                       const int* __restrict__ ei, const int* __restrict__ ea_ids,
                       float* __restrict__ gagg) {
    int idx = blockIdx.x * 256 + threadIdx.x;
    int e = idx >> 7, c = idx & 127;
    int s = ei[e], d = ei[E_GLOB + e];
    float v = fmaxf(gpool[s * H + c] + bond_emb[(ea_ids[e] - 1) * H + c], 0.f);
    atomicAdd(&gagg[d * H + c], v);
}

__global__ void k_aggz(const bf16* __restrict__ h, const float* __restrict__ gagg,
                       const float* __restrict__ bond_emb, const int* __restrict__ node_ids,
                       const int* __restrict__ rp, const int* __restrict__ deg,
                       const int* __restrict__ payload, bf16* __restrict__ z) {
    int idx = blockIdx.x * 256 + threadIdx.x;
    int f = idx >> 4, c8 = (idx & 15) << 3;
    int n = min(max(node_ids[f], 0), N_TOTAL - 1);
    float acc[8];
    s16x8 hv = *(const s16x8*)(h + (size_t)f * H + c8);
    const float* gg = gagg + (size_t)n * H + c8;
    #pragma unroll
    for (int j = 0; j < 8; ++j) acc[j] = rb2f(hv[j]) + gg[j];
    int beg = rp[f], end = beg + deg[f];
    for (int e = beg; e < end; ++e) {
        int p = payload[e];
        int src = p >> 3, ea = (p & 7) - 1;
        s16x8 hs = *(const s16x8*)(h + (size_t)src * H + c8);
        const float* be = bond_emb + ea * H + c8;
        #pragma unroll
        for (int j = 0; j < 8; ++j) acc[j] += fmaxf(rb2f(hs[j]) + be[j], 0.f);
    }
    s16x8 o;
    #pragma unroll
    for (int j = 0; j < 8; ++j) o[j] = (short)f2bu(acc[j]);
    *(s16x8*)(z + (size_t)f * H + c8) = o;
}

// Fused GINE MLP: h = (h + W2@relu(W1@z + b1) + b2) * valid, bf16 MFMA.
#define LDW 136

__global__ __launch_bounds__(256) void k_mlp_fused(
    const float* __restrict__ W1, const float* __restrict__ b1,
    const float* __restrict__ W2, const float* __restrict__ b2,
    const bf16* __restrict__ z, const int* __restrict__ node_ids,
    bf16* __restrict__ h) {
    __shared__ unsigned short zt[128][LDW];
    __shared__ unsigned short mt[128][LDW];
    __shared__ float validf[128];

    int tid = threadIdx.x;
    int w = tid >> 6;
    int l = tid & 63;
    int brow0 = blockIdx.x * 128;

    {
        int r = tid >> 1, c0 = (tid & 1) * 64;
        const s16x8* zr = (const s16x8*)(z + (size_t)(brow0 + r) * H + c0);
        #pragma unroll
        for (int i = 0; i < 8; ++i)
            *(s16x8*)&zt[r][c0 + i * 8] = zr[i];
        if (tid < 128) validf[tid] = (node_ids[brow0 + tid] >= 0) ? 1.f : 0.f;
    }

    s16x8 bw1[2][4], bw2[2][4];
    float b1c[2], b2c[2];
    #pragma unroll
    for (int nt = 0; nt < 2; ++nt) {
        int col = w * 32 + nt * 16 + (l & 15);
        b1c[nt] = b1[col];
        b2c[nt] = b2[col];
        #pragma unroll
        for (int kt = 0; kt < 4; ++kt) {
            int k0 = kt * 32 + (l >> 4) * 8;
            #pragma unroll
            for (int j = 0; j < 8; ++j) {
                bw1[nt][kt][j] = (short)f2bu(W1[(size_t)(k0 + j) * H + col]);
                bw2[nt][kt][j] = (short)f2bu(W2[(size_t)(k0 + j) * H + col]);
            }
        }
    }
    __syncthreads();

    f32x4 acc[8][2];
    #pragma unroll
    for (int mt_i = 0; mt_i < 8; ++mt_i)
        #pragma unroll
        for (int nt = 0; nt < 2; ++nt)
            acc[mt_i][nt] = f32x4{0.f, 0.f, 0.f, 0.f};
    #pragma unroll
    for (int kt = 0; kt < 4; ++kt) {
        #pragma unroll
        for (int mt_i = 0; mt_i < 8; ++mt_i) {
            s16x8 a = *(const s16x8*)&zt[mt_i * 16 + (l & 15)][kt * 32 + (l >> 4) * 8];
            acc[mt_i][0] = __builtin_amdgcn_mfma_f32_16x16x32_bf16(a, bw1[0][kt], acc[mt_i][0], 0, 0, 0);
            acc[mt_i][1] = __builtin_amdgcn_mfma_f32_16x16x32_bf16(a, bw1[1][kt], acc[mt_i][1], 0, 0, 0);
        }
    }
    #pragma unroll
    for (int mt_i = 0; mt_i < 8; ++mt_i) {
        #pragma unroll
        for (int nt = 0; nt < 2; ++nt) {
            int col = w * 32 + nt * 16 + (l & 15);
            #pragma unroll
            for (int r = 0; r < 4; ++r) {
                int row = mt_i * 16 + (l >> 4) * 4 + r;
                mt[row][col] = f2bu(fmaxf(acc[mt_i][nt][r] + b1c[nt], 0.f));
            }
        }
    }
    __syncthreads();

    #pragma unroll
    for (int mt_i = 0; mt_i < 8; ++mt_i)
        #pragma unroll
        for (int nt = 0; nt < 2; ++nt)
            acc[mt_i][nt] = f32x4{0.f, 0.f, 0.f, 0.f};
    #pragma unroll
    for (int kt = 0; kt < 4; ++kt) {
        #pragma unroll
        for (int mt_i = 0; mt_i < 8; ++mt_i) {
            s16x8 a = *(const s16x8*)&mt[mt_i * 16 + (l & 15)][kt * 32 + (l >> 4) * 8];
            acc[mt_i][0] = __builtin_amdgcn_mfma_f32_16x16x32_bf16(a, bw2[0][kt], acc[mt_i][0], 0, 0, 0);
            acc[mt_i][1] = __builtin_amdgcn_mfma_f32_16x16x32_bf16(a, bw2[1][kt], acc[mt_i][1], 0, 0, 0);
        }
    }
    #pragma unroll
    for (int mt_i = 0; mt_i < 8; ++mt_i) {
        #pragma unroll
        for (int nt = 0; nt < 2; ++nt) {
            int col = w * 32 + nt * 16 + (l & 15);
            #pragma unroll
            for (int r = 0; r < 4; ++r) {
                int row = mt_i * 16 + (l >> 4) * 4 + r;
                size_t g = (size_t)(brow0 + row) * H + col;
                float hv = b2f(h[g]);
                h[g] = f2b((hv + acc[mt_i][nt][r] + b2c[nt]) * validf[row]);
            }
        }
    }
}

// ------------------------------------------------------------- Readout ---

__global__ void k_tok(const bf16* __restrict__ h, float* __restrict__ htok) {
    int idx = blockIdx.x * 256 + threadIdx.x;
    int s = idx >> 7, c = idx & 127;
    htok[idx] = b2f(h[(size_t)s * K_SUB * H + c]);
}

// K1: LN1 + QKV(MFMA) + attention + Wo(MFMA) + residual.
// Block: 256 thr (4 waves), 64 token rows (16 nodes). Grid: 16384/64 = 256.
#define ROQ_STR 408

__global__ __launch_bounds__(256) void k_ro_attn(
    float* __restrict__ htok,
    const float* __restrict__ g1, const float* __restrict__ b1,
    const float* __restrict__ Wqkv, const float* __restrict__ bqkv,
    const float* __restrict__ Wo, const float* __restrict__ bo,
    const float* __restrict__ log_probs, const float* __restrict__ alpha_p) {
    __shared__ unsigned short xn[64][LDW];     // LN output, then o buffer
    __shared__ unsigned short qkv[64][ROQ_STR];
    __shared__ float lpv[64];
    int tid = threadIdx.x;
    int w = tid >> 6, l = tid & 63;
    int g0 = blockIdx.x * 64;                  // first token row
    float alpha = alpha_p[0];

    // --- LN1: htok (fp32) -> xn (bf16) ---
    {
        int t = tid >> 2, q = tid & 3;
        const float4* xr = (const float4*)(htok + (size_t)(g0 + t) * H + q * 32);
        float x[32]; float s = 0.f, ss = 0.f;
        #pragma unroll
        for (int i = 0; i < 8; ++i) {
            float4 v = xr[i];
            x[i * 4 + 0] = v.x; x[i * 4 + 1] = v.y; x[i * 4 + 2] = v.z; x[i * 4 + 3] = v.w;
            s += v.x + v.y + v.z + v.w;
            ss += v.x * v.x + v.y * v.y + v.z * v.z + v.w * v.w;
        }
        s += __shfl_xor(s, 1); ss += __shfl_xor(ss, 1);
        s += __shfl_xor(s, 2); ss += __shfl_xor(ss, 2);
        float mu = s * (1.f / 128.f);
        float var = ss * (1.f / 128.f) - mu * mu;
        float inv = rsqrtf(var + 1e-5f);
        #pragma unroll
        for (int i = 0; i < 32; ++i) {
            int c = q * 32 + i;
            xn[t][c] = f2bu((x[i] - mu) * inv * g1[c] + b1[c]);
        }
        if (tid < 64) {
            float lp = log_probs[g0 + tid];
            lpv[tid] = isfinite(lp) ? lp : 0.f;
        }
    }
    __syncthreads();

    // --- A-fragments from xn (held in regs for all QKV column chunks) ---
    s16x8 a[4][4];
    #pragma unroll
    for (int mt_i = 0; mt_i < 4; ++mt_i)
        #pragma unroll
        for (int kt = 0; kt < 4; ++kt)
            a[mt_i][kt] = *(const s16x8*)&xn[mt_i * 16 + (l & 15)][kt * 32 + (l >> 4) * 8];

    // --- QKV GEMM: wave w owns cols [w*96, w*96+96) of 384 ---
    #pragma unroll
    for (int nt = 0; nt < 6; ++nt) {
        int col = w * 96 + nt * 16 + (l & 15);
        s16x8 bw[4];
        #pragma unroll
        for (int kt = 0; kt < 4; ++kt) {
            int k0 = kt * 32 + (l >> 4) * 8;
            #pragma unroll
            for (int j = 0; j < 8; ++j)
                bw[kt][j] = (short)f2bu(Wqkv[(size_t)(k0 + j) * 384 + col]);
        }
        f32x4 acc[4];
        #pragma unroll
        for (int mt_i = 0; mt_i < 4; ++mt_i) acc[mt_i] = f32x4{0.f, 0.f, 0.f, 0.f};
        #pragma unroll
        for (int kt = 0; kt < 4; ++kt)
            #pragma unroll
            for (int mt_i = 0; mt_i < 4; ++mt_i)
                acc[mt_i] = __builtin_amdgcn_mfma_f32_16x16x32_bf16(a[mt_i][kt], bw[kt], acc[mt_i], 0, 0, 0);
        float bb = bqkv[col];
        #pragma unroll
        for (int mt_i = 0; mt_i < 4; ++mt_i)
            #pragma unroll
            for (int r = 0; r < 4; ++r)
                qkv[mt_i * 16 + (l >> 4) * 4 + r][col] = f2bu(acc[mt_i][r] + bb);
    }
    __syncthreads();

    // --- attention: thread = (node, head, query-row); all in registers ---
    {
        int node = tid >> 4, hh = (tid >> 2) & 3, ii = tid & 3;
        int t0 = node * 4;
        float qv[32];
        #pragma unroll
        for (int j4 = 0; j4 < 4; ++j4) {
            s16x8 v = *(const s16x8*)&qkv[t0 + ii][hh * 32 + j4 * 8];
            #pragma unroll
            for (int j = 0; j < 8; ++j) qv[j4 * 8 + j] = rb2f(v[j]);
        }
        float sc[4];
        #pragma unroll
        for (int jj = 0; jj < 4; ++jj) {
            float d = 0.f;
            #pragma unroll
            for (int j4 = 0; j4 < 4; ++j4) {
                s16x8 kv = *(const s16x8*)&qkv[t0 + jj][128 + hh * 32 + j4 * 8];
                #pragma unroll
                for (int j = 0; j < 8; ++j) d += qv[j4 * 8 + j] * rb2f(kv[j]);
            }
            sc[jj] = d * 0.17677669529663689f + alpha * lpv[t0 + jj];
        }
        float mx = fmaxf(fmaxf(sc[0], sc[1]), fmaxf(sc[2], sc[3]));
        float p[4]; float se = 0.f;
        #pragma unroll
        for (int jj = 0; jj < 4; ++jj) { p[jj] = expf(sc[jj] - mx); se += p[jj]; }
        float inv = 1.f / se;
        #pragma unroll
        for (int jj = 0; jj < 4; ++jj) p[jj] *= inv;
        float ov[32];
        #pragma unroll
        for (int i = 0; i < 32; ++i) ov[i] = 0.f;
        #pragma unroll
        for (int jj = 0; jj < 4; ++jj) {
            #pragma unroll
            for (int j4 = 0; j4 < 4; ++j4) {
                s16x8 vv = *(const s16x8*)&qkv[t0 + jj][256 + hh * 32 + j4 * 8];
                #pragma unroll
                for (int j = 0; j < 8; ++j) ov[j4 * 8 + j] += p[jj] * rb2f(vv[j]);
            }
        }
        __syncthreads();   // all reads of qkv done; xn free to overwrite
        #pragma unroll
        for (int j4 = 0; j4 < 4; ++j4) {
            s16x8 o8;
            #pragma unroll
            for (int j = 0; j < 8; ++j) o8[j] = (short)f2bu(ov[j4 * 8 + j]);
            *(s16x8*)&xn[t0 + ii][hh * 32 + j4 * 8] = o8;
        }
    }
    __syncthreads();

    // --- Wo GEMM + residual: htok += o @ Wo + bo ---
    s16x8 ao[4][4];
    #pragma unroll
    for (int mt_i = 0; mt_i < 4; ++mt_i)
        #pragma unroll
        for (int kt = 0; kt < 4; ++kt)
            ao[mt_i][kt] = *(const s16x8*)&xn[mt_i * 16 + (l & 15)][kt * 32 + (l >> 4) * 8];
    #pragma unroll
    for (int nt = 0; nt < 2; ++nt) {
        int col = w * 32 + nt * 16 + (l & 15);
        s16x8 bw[4];
        #pragma unroll
        for (int kt = 0; kt < 4; ++kt) {
            int k0 = kt * 32 + (l >> 4) * 8;
            #pragma unroll
            for (int j = 0; j < 8; ++j)
                bw[kt][j] = (short)f2bu(Wo[(size_t)(k0 + j) * H + col]);
        }
        f32x4 acc[4];
        #pragma unroll
        for (int mt_i = 0; mt_i < 4; ++mt_i) acc[mt_i] = f32x4{0.f, 0.f, 0.f, 0.f};
        #pragma unroll
        for (int kt = 0; kt < 4; ++kt)
            #pragma unroll
            for (int mt_i = 0; mt_i < 4; ++mt_i)
                acc[mt_i] = __builtin_amdgcn_mfma_f32_16x16x32_bf16(ao[mt_i][kt], bw[kt], acc[mt_i], 0, 0, 0);
        float bb = bo[col];
        #pragma unroll
        for (int mt_i = 0; mt_i < 4; ++mt_i)
            #pragma unroll
            for (int r = 0; r < 4; ++r) {
                int row = mt_i * 16 + (l >> 4) * 4 + r;
                size_t gg = (size_t)(g0 + row) * H + col;
                htok[gg] += acc[mt_i][r] + bb;
            }
    }
}

// K2: LN2 + FFN1(gelu) + FFN2 (K-blocked) + residual.
__global__ __launch_bounds__(256) void k_ro_ffn(
    float* __restrict__ htok,
    const float* __restrict__ g2, const float* __restrict__ b2,
    const float* __restrict__ Wf1, const float* __restrict__ bf1,
    const float* __restrict__ Wf2, const float* __restrict__ bf2) {
    __shared__ unsigned short xb[64][LDW];     // LN output, then mid chunk
    int tid = threadIdx.x;
    int w = tid >> 6, l = tid & 63;
    int g0 = blockIdx.x * 64;

    // --- LN2 ---
    {
        int t = tid >> 2, q = tid & 3;
        const float4* xr = (const float4*)(htok + (size_t)(g0 + t) * H + q * 32);
        float x[32]; float s = 0.f, ss = 0.f;
        #pragma unroll
        for (int i = 0; i < 8; ++i) {
            float4 v = xr[i];
            x[i * 4 + 0] = v.x; x[i * 4 + 1] = v.y; x[i * 4 + 2] = v.z; x[i * 4 + 3] = v.w;
            s += v.x + v.y + v.z + v.w;
            ss += v.x * v.x + v.y * v.y + v.z * v.z + v.w * v.w;
        }
        s += __shfl_xor(s, 1); ss += __shfl_xor(ss, 1);
        s += __shfl_xor(s, 2); ss += __shfl_xor(ss, 2);
        float mu = s * (1.f / 128.f);
        float var = ss * (1.f / 128.f) - mu * mu;
        float inv = rsqrtf(var + 1e-5f);
        #pragma unroll
        for (int i = 0; i < 32; ++i) {
            int c = q * 32 + i;
            xb[t][c] = f2bu((x[i] - mu) * inv * g2[c] + b2[c]);
        }
    }
    __syncthreads();

    s16x8 a2[4][4];
    #pragma unroll
    for (int mt_i = 0; mt_i < 4; ++mt_i)
        #pragma unroll
        for (int kt = 0; kt < 4; ++kt)
            a2[mt_i][kt] = *(const s16x8*)&xb[mt_i * 16 + (l & 15)][kt * 32 + (l >> 4) * 8];
    __syncthreads();   // a2 loaded; xb free for mid chunks

    f32x4 acc2[4][2];
    #pragma unroll
    for (int mt_i = 0; mt_i < 4; ++mt_i)
        #pragma unroll
        for (int nt = 0; nt < 2; ++nt)
            acc2[mt_i][nt] = f32x4{0.f, 0.f, 0.f, 0.f};

    #pragma unroll
    for (int cc = 0; cc < 4; ++cc) {
        // FFN1 chunk: mid[:, cc*128 : cc*128+128] = gelu(xn @ Wf1 + bf1)
        #pragma unroll
        for (int nt = 0; nt < 2; ++nt) {
            int colf = cc * 128 + w * 32 + nt * 16 + (l & 15);
            s16x8 bw[4];
            #pragma unroll
            for (int kt = 0; kt < 4; ++kt) {
                int k0 = kt * 32 + (l >> 4) * 8;
                #pragma unroll
                for (int j = 0; j < 8; ++j)
                    bw[kt][j] = (short)f2bu(Wf1[(size_t)(k0 + j) * FFN + colf]);
            }
            f32x4 accm[4];
            #pragma unroll
            for (int mt_i = 0; mt_i < 4; ++mt_i) accm[mt_i] = f32x4{0.f, 0.f, 0.f, 0.f};
            #pragma unroll
            for (int kt = 0; kt < 4; ++kt)
                #pragma unroll
                for (int mt_i = 0; mt_i < 4; ++mt_i)
                    accm[mt_i] = __builtin_amdgcn_mfma_f32_16x16x32_bf16(a2[mt_i][kt], bw[kt], accm[mt_i], 0, 0, 0);
            float bb = bf1[colf];
            int colw = w * 32 + nt * 16 + (l & 15);
            #pragma unroll
            for (int mt_i = 0; mt_i < 4; ++mt_i)
                #pragma unroll
                for (int r = 0; r < 4; ++r) {
                    float v = accm[mt_i][r] + bb;
                    v = v * 0.5f * (1.f + erff(v * 0.70710678118654752f));
                    xb[mt_i * 16 + (l >> 4) * 4 + r][colw] = f2bu(v);
                }
        }
        __syncthreads();
        // FFN2 partial: acc2 += mid_chunk @ Wf2[cc*128 : cc*128+128, :]
        s16x8 am[4][4];
        #pragma unroll
        for (int mt_i = 0; mt_i < 4; ++mt_i)
            #pragma unroll
            for (int kt = 0; kt < 4; ++kt)
                am[mt_i][kt] = *(const s16x8*)&xb[mt_i * 16 + (l & 15)][kt * 32 + (l >> 4) * 8];
        #pragma unroll
        for (int nt = 0; nt < 2; ++nt) {
            int colo = w * 32 + nt * 16 + (l & 15);
            s16x8 bw[4];
            #pragma unroll
            for (int kt = 0; kt < 4; ++kt) {
                int k0 = cc * 128 + kt * 32 + (l >> 4) * 8;
                #pragma unroll
                for (int j = 0; j < 8; ++j)
                    bw[kt][j] = (short)f2bu(Wf2[(size_t)(k0 + j) * H + colo]);
            }
            #pragma unroll
            for (int kt = 0; kt < 4; ++kt)
                #pragma unroll
                for (int mt_i = 0; mt_i < 4; ++mt_i)
                    acc2[mt_i][nt] = __builtin_amdgcn_mfma_f32_16x16x32_bf16(am[mt_i][kt], bw[kt], acc2[mt_i][nt], 0, 0, 0);
        }
        __syncthreads();
    }

    // --- residual epilogue ---
    #pragma unroll
    for (int nt = 0; nt < 2; ++nt) {
        int col = w * 32 + nt * 16 + (l & 15);
        float bb = bf2[col];
        #pragma unroll
        for (int mt_i = 0; mt_i < 4; ++mt_i)
            #pragma unroll
            for (int r = 0; r < 4; ++r) {
                int row = mt_i * 16 + (l >> 4) * 4 + r;
                size_t gg = (size_t)(g0 + row) * H + col;
                htok[gg] += acc2[mt_i][nt][r] + bb;
            }
    }
}

__global__ __launch_bounds__(128) void k_nodeemb(const float* __restrict__ htok,
                                                 const float* __restrict__ og,
                                                 const float* __restrict__ ob,
                                                 float* __restrict__ nemb) {
    int n = blockIdx.x, c = threadIdx.x;
    const float* hr = htok + (size_t)n * 4 * H;
    float v = 0.25f * (hr[c] + hr[H + c] + hr[2 * H + c] + hr[3 * H + c]);
    float s = v, ss = v * v;
    #pragma unroll
    for (int m = 1; m < 64; m <<= 1) { s += __shfl_xor(s, m); ss += __shfl_xor(ss, m); }
    __shared__ float red[4];
    if ((threadIdx.x & 63) == 0) {
        red[(threadIdx.x >> 6) * 2] = s;
        red[(threadIdx.x >> 6) * 2 + 1] = ss;
    }
    __syncthreads();
    s = red[0] + red[2];
    ss = red[1] + red[3];
    float mu = s * (1.f / 128.f);
    float var = ss * (1.f / 128.f) - mu * mu;
    float inv = rsqrtf(var + 1e-5f);
    nemb[(size_t)n * H + c] = (v - mu) * inv * og[c] + ob[c];
}

__global__ __launch_bounds__(128) void k_out(const float* __restrict__ nemb,
                                             float* __restrict__ out) {
    int g = blockIdx.x, c = threadIdx.x;
    float acc = 0.f;
    for (int i = 0; i < 128; ++i) acc += nemb[(size_t)(g * 128 + i) * H + c];
    out[g * H + c] = acc;
}

// ------------------------------------------------------------- launch ----

extern "C" void kernel_launch(void* const* d_in, const int* in_sizes, int n_in,
                              void* d_out, int out_size, void* d_ws, size_t ws_size,
                              hipStream_t stream) {
    (void)in_sizes; (void)n_in; (void)out_size;
    const int* edge_index    = (const int*)d_in[0];
    const int* intra_ei      = (const int*)d_in[1];
    const int* edge_attr_ids = (const int*)d_in[2];
    const int* intra_ea_ids  = (const int*)d_in[3];
    const int* node_ids      = (const int*)d_in[4];
    const int* x_ids         = (const int*)d_in[5];
    const float* log_probs   = (const float*)d_in[7];
    const float* atom_emb    = (const float*)d_in[8];
    const float* bond_emb    = (const float*)d_in[9];
    const float* rwse_W      = (const float*)d_in[10];
    const float* rwse_b      = (const float*)d_in[11];
    const float* gnn_W1      = (const float*)d_in[12];
    const float* gnn_b1      = (const float*)d_in[13];
    const float* gnn_W2      = (const float*)d_in[14];
    const float* gnn_b2      = (const float*)d_in[15];
    const float* ro_ln1_g    = (const float*)d_in[16];
    const float* ro_ln1_b    = (const float*)d_in[17];
    const float* ro_Wqkv     = (const float*)d_in[18];
    const float* ro_bqkv     = (const float*)d_in[19];
    const float* ro_Wo       = (const float*)d_in[20];
    const float* ro_bo       = (const float*)d_in[21];
    const float* ro_ln2_g    = (const float*)d_in[22];
    const float* ro_ln2_b    = (const float*)d_in[23];
    const float* ro_Wf1      = (const float*)d_in[24];
    const float* ro_bf1      = (const float*)d_in[25];
    const float* ro_Wf2      = (const float*)d_in[26];
    const float* ro_bf2      = (const float*)d_in[27];
    const float* out_ln_g    = (const float*)d_in[28];
    const float* out_ln_b    = (const float*)d_in[29];
    const float* ht_alpha    = (const float*)d_in[30];

    char* ws = (char*)d_ws;
    size_t off = 0;
    auto alloc = [&](size_t nbytes) {
        char* p = ws + off;
        off += (nbytes + 255) & ~(size_t)255;
        return p;
    };
    float* T       = (float*)alloc((size_t)B_GRAPHS * 128 * 128 * 4);
    float* rwse    = (float*)alloc((size_t)N_TOTAL * STEPS * 4);
    float* base    = (float*)alloc((size_t)N_TOTAL * H * 4);
    float* gbuf    = (float*)alloc((size_t)2 * N_TOTAL * H * 4);
    float* htok    = (float*)alloc((size_t)S_SUB * H * 4);
    float* nemb    = (float*)alloc((size_t)N_TOTAL * H * 4);
    bf16*  z       = (bf16*)alloc((size_t)FLATN * H * 2);
    bf16*  h       = (bf16*)alloc((size_t)FLATN * H * 2);
    int*   deg     = (int*)alloc((size_t)FLATN * 4);
    int*   rp      = (int*)alloc((size_t)FLATN * 4);
    int*   cursor  = (int*)alloc((size_t)FLATN * 4);
    int*   payload = (int*)alloc((size_t)E_INTRA * 4);
    int*   degN    = (int*)alloc((size_t)N_TOTAL * 4);
    int*   rpN     = (int*)alloc((size_t)N_TOTAL * 4);
    int*   cursorN = (int*)alloc((size_t)N_TOTAL * 4);
    int*   poolidx = (int*)alloc((size_t)FLATN * 4);
    int*   bsum    = (int*)alloc(1024 * 4);
    int*   bsumN   = (int*)alloc(16 * 4);
    float* gpool   = gbuf;
    float* gagg    = gbuf + (size_t)N_TOTAL * H;

    if (off > ws_size) return;

    // ---- CSR build ----
    k_zeroi<<<FLATN / 256, 256, 0, stream>>>(deg, FLATN);
    k_zeroi<<<N_TOTAL / 256, 256, 0, stream>>>(degN, N_TOTAL);
    k_hist_edge<<<E_INTRA / 256, 256, 0, stream>>>(intra_ei, deg);
    k_hist_pool<<<FLATN / 256, 256, 0, stream>>>(node_ids, degN);
    k_scan_blk<<<FLATN / 256, 256, 0, stream>>>(deg, rp, bsum, FLATN);
    k_scan_top<<<1, 256, 0, stream>>>(bsum, FLATN / 256);
    k_scan_add<<<FLATN / 256, 256, 0, stream>>>(rp, bsum, cursor, FLATN);
    k_scan_blk<<<N_TOTAL / 256, 256, 0, stream>>>(degN, rpN, bsumN, N_TOTAL);
    k_scan_top<<<1, 256, 0, stream>>>(bsumN, N_TOTAL / 256);
    k_scan_add<<<N_TOTAL / 256, 256, 0, stream>>>(rpN, bsumN, cursorN, N_TOTAL);
    k_scatter_edge<<<E_INTRA / 256, 256, 0, stream>>>(intra_ei, intra_ea_ids, cursor, payload);
    k_scatter_pool<<<FLATN / 256, 256, 0, stream>>>(node_ids, cursorN, poolidx);

    // ---- RWSE ----
    k_zero4<<<(B_GRAPHS * 128 * 128 / 4 + 255) / 256, 256, 0, stream>>>((float4*)T, B_GRAPHS * 128 * 128 / 4);
    k_adj<<<E_GLOB / 256, 256, 0, stream>>>(edge_index, T);
    k_rownorm<<<(B_GRAPHS * 128) / 4, 256, 0, stream>>>(T);
    k_rwse_chain<<<B_GRAPHS * RW_BPG, 128, 0, stream>>>(T, rwse);
    k_rwse_head<<<(N_TOTAL * H) / 256, 256, 0, stream>>>(rwse, rwse_W, rwse_b, atom_emb, x_ids, base);
    k_hinit<<<(FLATN * H) / 256, 256, 0, stream>>>(base, node_ids, h);

    // ---- GNN layers ----
    for (int l = 0; l < L_GNN; ++l) {
        k_zero4<<<(N_TOTAL * H / 4 + 255) / 256, 256, 0, stream>>>((float4*)gagg, N_TOTAL * H / 4);
        k_pool_csr<<<(N_TOTAL * H) / 256, 256, 0, stream>>>(h, rpN, degN, poolidx, gpool);
        k_gagg<<<(E_GLOB * H) / 256, 256, 0, stream>>>(gpool, bond_emb, edge_index, edge_attr_ids, gagg);
        k_aggz<<<(FLATN * 16) / 256, 256, 0, stream>>>(h, gagg, bond_emb, node_ids, rp, deg, payload, z);
        k_mlp_fused<<<FLATN / 128, 256, 0, stream>>>(
            gnn_W1 + (size_t)l * H * H, gnn_b1 + l * H,
            gnn_W2 + (size_t)l * H * H, gnn_b2 + l * H,
            z, node_ids, h);
    }

    // ---- Readout ----
    k_tok<<<(S_SUB * H) / 256, 256, 0, stream>>>(h, htok);
    for (int l = 0; l < L_RO; ++l) {
        k_ro_attn<<<S_SUB * M_TOK / 64 / 4, 256, 0, stream>>>(htok,
            ro_ln1_g + l * H, ro_ln1_b + l * H,
            ro_Wqkv + (size_t)l * H * 3 * H, ro_bqkv + l * 3 * H,
            ro_Wo + (size_t)l * H * H, ro_bo + l * H,
            log_probs, ht_alpha);
        k_ro_ffn<<<S_SUB * M_TOK / 64 / 4, 256, 0, stream>>>(htok,
            ro_ln2_g + l * H, ro_ln2_b + l * H,
            ro_Wf1 + (size_t)l * H * FFN, ro_bf1 + l * FFN,
            ro_Wf2 + (size_t)l * FFN * H, ro_bf2 + l * H);
    }
    k_nodeemb<<<N_TOTAL, 128, 0, stream>>>(htok, out_ln_g, out_ln_b, nemb);
    k_out<<<B_GRAPHS, 128, 0, stream>>>(nemb, (float*)d_out);
}

// Round 6
// 1014.220 us; speedup vs baseline: 5.1848x; 1.1275x over previous
//
#include <hip/hip_runtime.h>
#include <hip/hip_bf16.h>
#include <math.h>

#define B_GRAPHS 32
#define NPG 128
#define N_TOTAL 4096
#define M_TOK 4
#define K_SUB 16
#define S_SUB 16384
#define FLATN 262144
#define H 128
#define NH 4
#define DH 32
#define STEPS 16
#define L_GNN 4
#define L_RO 2
#define EDGE_DIM 5
#define E_GLOB 32768
#define E_INTRA 524288
#define FFN 512
#define LDW 136

typedef __hip_bfloat16 bf16;
typedef __attribute__((ext_vector_type(8))) short s16x8;
typedef __attribute__((ext_vector_type(4))) float f32x4;

__device__ __forceinline__ float b2f(bf16 v) { return __bfloat162float(v); }
__device__ __forceinline__ bf16 f2b(float v) { return __float2bfloat16(v); }
__device__ __forceinline__ unsigned short f2bu(float v) {
    bf16 b = __float2bfloat16(v);
    return *(unsigned short*)&b;
}
__device__ __forceinline__ float rb2f(short u) {
    return __uint_as_float(((unsigned int)(unsigned short)u) << 16);
}

// ------------------------------------------------------------- utility ---

__global__ void k_zero4(float4* __restrict__ p, int n4) {
    int i = blockIdx.x * 256 + threadIdx.x;
    if (i < n4) p[i] = make_float4(0.f, 0.f, 0.f, 0.f);
}

__global__ void k_zeroi(int* __restrict__ p, int n) {
    int i = blockIdx.x * 256 + threadIdx.x;
    if (i < n) p[i] = 0;
}

// ------------------------------------------------------------ CSR build --

__global__ void k_hist_edge(const int* __restrict__ iei, int* __restrict__ deg) {
    int e = blockIdx.x * 256 + threadIdx.x;
    if (e < E_INTRA) atomicAdd(&deg[iei[E_INTRA + e]], 1);
}

__global__ void k_hist_pool(const int* __restrict__ nid, int* __restrict__ degN) {
    int f = blockIdx.x * 256 + threadIdx.x;
    if (f < FLATN) atomicAdd(&degN[min(max(nid[f], 0), N_TOTAL - 1)], 1);
}

__global__ __launch_bounds__(256) void k_scan_blk(const int* __restrict__ in,
                                                  int* __restrict__ out,
                                                  int* __restrict__ bsum, int n) {
    __shared__ int s[256];
    int i = blockIdx.x * 256 + threadIdx.x;
    int v = (i < n) ? in[i] : 0;
    s[threadIdx.x] = v;
    __syncthreads();
    #pragma unroll
    for (int off = 1; off < 256; off <<= 1) {
        int t = (threadIdx.x >= off) ? s[threadIdx.x - off] : 0;
        __syncthreads();
        s[threadIdx.x] += t;
        __syncthreads();
    }
    if (i < n) out[i] = s[threadIdx.x] - v;
    if (threadIdx.x == 255) bsum[blockIdx.x] = s[255];
}

__global__ __launch_bounds__(256) void k_scan_top(int* __restrict__ bsum, int nb) {
    __shared__ int s[256];
    int base = threadIdx.x * 4;
    int v[4]; int loc = 0;
    #pragma unroll
    for (int j = 0; j < 4; ++j) {
        v[j] = (base + j < nb) ? bsum[base + j] : 0;
        loc += v[j];
    }
    s[threadIdx.x] = loc;
    __syncthreads();
    #pragma unroll
    for (int off = 1; off < 256; off <<= 1) {
        int t = (threadIdx.x >= off) ? s[threadIdx.x - off] : 0;
        __syncthreads();
        s[threadIdx.x] += t;
        __syncthreads();
    }
    int run = s[threadIdx.x] - loc;
    #pragma unroll
    for (int j = 0; j < 4; ++j) {
        if (base + j < nb) bsum[base + j] = run;
        run += v[j];
    }
}

__global__ void k_scan_add(int* __restrict__ out, const int* __restrict__ bsum,
                           int* __restrict__ cursor, int n) {
    int i = blockIdx.x * 256 + threadIdx.x;
    if (i < n) {
        int v = out[i] + bsum[i >> 8];
        out[i] = v;
        cursor[i] = v;
    }
}

__global__ void k_scatter_edge(const int* __restrict__ iei, const int* __restrict__ iea,
                               int* __restrict__ cursor, int* __restrict__ payload) {
    int e = blockIdx.x * 256 + threadIdx.x;
    if (e >= E_INTRA) return;
    int d = iei[E_INTRA + e];
    int pos = atomicAdd(&cursor[d], 1);
    payload[pos] = (iei[e] << 3) | iea[e];
}

__global__ void k_scatter_pool(const int* __restrict__ nid, int* __restrict__ cursorN,
                               int* __restrict__ poolidx) {
    int f = blockIdx.x * 256 + threadIdx.x;
    if (f >= FLATN) return;
    int n = min(max(nid[f], 0), N_TOTAL - 1);
    int pos = atomicAdd(&cursorN[n], 1);
    poolidx[pos] = f;
}

// ---------------------------------------------------------------- RWSE ----

__global__ void k_adj(const int* __restrict__ ei, float* __restrict__ T) {
    int e = blockIdx.x * 256 + threadIdx.x;
    if (e >= E_GLOB) return;
    int s = ei[e], d = ei[E_GLOB + e];
    int g = s >> 7;
    atomicAdd(&T[(g * 128 + (s & 127)) * 128 + (d & 127)], 1.0f);
}

__global__ void k_rownorm(float* __restrict__ T) {
    int row = blockIdx.x * 4 + (threadIdx.x >> 6);
    int lane = threadIdx.x & 63;
    float* r = T + (size_t)row * 128;
    float v0 = r[lane], v1 = r[lane + 64];
    float s = v0 + v1;
    #pragma unroll
    for (int off = 32; off > 0; off >>= 1) s += __shfl_down(s, off);
    s = __shfl(s, 0);
    float inv = 1.0f / fmaxf(s, 1.0f);
    r[lane] = v0 * inv;
    r[lane + 64] = v1 * inv;
}

// Matrix-power chain via MFMA. Row chains are independent: split M.
// Grid: 32 graphs x 4 row-blocks (32 rows each). Block 256 thr (4 waves).
// B-operand (T columns, bf16) lives in registers across all 15 steps;
// P-tile ping-pongs in LDS; diag extracted from fp32 accumulator.
#define RWG 4
#define RWM 32

__global__ __launch_bounds__(256) void k_rwse_mfma(const float* __restrict__ T,
                                                   float* __restrict__ rwse) {
    __shared__ unsigned short P[2][RWM][LDW];
    int g = blockIdx.x / RWG, rb = blockIdx.x % RWG;
    int row0 = rb * RWM;
    int tid = threadIdx.x;
    int w = tid >> 6, l = tid & 63;
    const float* Tg = T + (size_t)g * 16384;

    // stage P0 = bf16(T[row0:row0+32, :])
    {
        int r = tid >> 3;
        int c0 = (tid & 7) * 16;
        const float4* src = (const float4*)(Tg + (size_t)(row0 + r) * 128 + c0);
        #pragma unroll
        for (int i = 0; i < 4; ++i) {
            float4 v = src[i];
            ushort4 u;
            u.x = f2bu(v.x); u.y = f2bu(v.y); u.z = f2bu(v.z); u.w = f2bu(v.w);
            *(ushort4*)&P[0][r][c0 + i * 4] = u;
        }
    }
    // diag(T^1) from fp32 global
    if (tid < RWM) {
        int gr = row0 + tid;
        rwse[(size_t)(g * 128 + gr) * STEPS] = Tg[(size_t)gr * 128 + gr];
    }

    // B-fragments: wave w owns cols [w*32, w*32+32)
    s16x8 bw[2][4];
    #pragma unroll
    for (int nt = 0; nt < 2; ++nt) {
        int col = w * 32 + nt * 16 + (l & 15);
        #pragma unroll
        for (int kt = 0; kt < 4; ++kt) {
            int k0 = kt * 32 + (l >> 4) * 8;
            #pragma unroll
            for (int j = 0; j < 8; ++j)
                bw[nt][kt][j] = (short)f2bu(Tg[(size_t)(k0 + j) * 128 + col]);
        }
    }
    __syncthreads();

    int cur = 0;
    for (int s = 1; s < STEPS; ++s) {
        f32x4 acc[2][2];
        #pragma unroll
        for (int mt_i = 0; mt_i < 2; ++mt_i)
            #pragma unroll
            for (int nt = 0; nt < 2; ++nt)
                acc[mt_i][nt] = f32x4{0.f, 0.f, 0.f, 0.f};
        #pragma unroll
        for (int kt = 0; kt < 4; ++kt) {
            #pragma unroll
            for (int mt_i = 0; mt_i < 2; ++mt_i) {
                s16x8 a = *(const s16x8*)&P[cur][mt_i * 16 + (l & 15)][kt * 32 + (l >> 4) * 8];
                acc[mt_i][0] = __builtin_amdgcn_mfma_f32_16x16x32_bf16(a, bw[0][kt], acc[mt_i][0], 0, 0, 0);
                acc[mt_i][1] = __builtin_amdgcn_mfma_f32_16x16x32_bf16(a, bw[1][kt], acc[mt_i][1], 0, 0, 0);
            }
        }
        #pragma unroll
        for (int mt_i = 0; mt_i < 2; ++mt_i) {
            #pragma unroll
            for (int nt = 0; nt < 2; ++nt) {
                int col = w * 32 + nt * 16 + (l & 15);
                #pragma unroll
                for (int r = 0; r < 4; ++r) {
                    int lrow = mt_i * 16 + (l >> 4) * 4 + r;
                    P[cur ^ 1][lrow][col] = f2bu(acc[mt_i][nt][r]);
                    if (row0 + lrow == col)
                        rwse[(size_t)(g * 128 + col) * STEPS + s] = acc[mt_i][nt][r];
                }
            }
        }
        __syncthreads();
        cur ^= 1;
    }
}

__global__ void k_rwse_head(const float* __restrict__ rwse, const float* __restrict__ rwse_W,
                            const float* __restrict__ rwse_b, const float* __restrict__ atom_emb,
                            const int* __restrict__ x_ids, float* __restrict__ base) {
    int idx = blockIdx.x * 256 + threadIdx.x;
    int n = idx >> 7, c = idx & 127;
    const float* r = rwse + (size_t)n * STEPS;
    float acc = rwse_b[c];
    #pragma unroll
    for (int s = 0; s < STEPS; ++s) acc += r[s] * rwse_W[s * H + c];
    acc = fmaxf(acc, 0.f);
    base[idx] = acc + atom_emb[x_ids[n] * H + c];
}

__global__ void k_hinit(const float* __restrict__ base, const int* __restrict__ node_ids,
                        bf16* __restrict__ h) {
    int idx = blockIdx.x * 256 + threadIdx.x;
    int f = idx >> 7, c = idx & 127;
    int nidv = node_ids[f];
    int n = min(max(nidv, 0), N_TOTAL - 1);
    float v = base[n * H + c];
    if (nidv < 0) v = 0.f;
    h[idx] = f2b(v);
}

// ---------------------------------------------------------------- GNN -----

__global__ void k_pool_csr(const bf16* __restrict__ h, const int* __restrict__ rpN,
                           const int* __restrict__ degN, const int* __restrict__ poolidx,
                           float* __restrict__ gpool) {
    int idx = blockIdx.x * 256 + threadIdx.x;
    int n = idx >> 7, c = idx & 127;
    float acc = 0.f;
    int beg = rpN[n], end = beg + degN[n];
    for (int j = beg; j < end; ++j) {
        int f = poolidx[j];
        acc += b2f(h[(size_t)f * H + c]);
    }
    gpool[idx] = acc;
}

__global__ void k_gagg(const float* __restrict__ gpool, const float* __restrict__ bond_emb,
                       const int* __restrict__ ei, const int* __restrict__ ea_ids,
                       float* __restrict__ gagg) {
    int idx = blockIdx.x * 256 + threadIdx.x;
    int e = idx >> 7, c = idx & 127;
    int s = ei[e], d = ei[E_GLOB + e];
    float v = fmaxf(gpool[s * H + c] + bond_emb[(ea_ids[e] - 1) * H + c], 0.f);
    atomicAdd(&gagg[d * H + c], v);
}

__global__ void k_aggz(const bf16* __restrict__ h, const float* __restrict__ gagg,
                       const float* __restrict__ bond_emb, const int* __restrict__ node_ids,
                       const int* __restrict__ rp, const int* __restrict__ deg,
                       const int* __restrict__ payload, bf16* __restrict__ z) {
    int idx = blockIdx.x * 256 + threadIdx.x;
    int f = idx >> 4, c8 = (idx & 15) << 3;
    int n = min(max(node_ids[f], 0), N_TOTAL - 1);
    float acc[8];
    s16x8 hv = *(const s16x8*)(h + (size_t)f * H + c8);
    const float* gg = gagg + (size_t)n * H + c8;
    #pragma unroll
    for (int j = 0; j < 8; ++j) acc[j] = rb2f(hv[j]) + gg[j];
    int beg = rp[f], end = beg + deg[f];
    for (int e = beg; e < end; ++e) {
        int p = payload[e];
        int src = p >> 3, ea = (p & 7) - 1;
        s16x8 hs = *(const s16x8*)(h + (size_t)src * H + c8);
        const float* be = bond_emb + ea * H + c8;
        #pragma unroll
        for (int j = 0; j < 8; ++j) acc[j] += fmaxf(rb2f(hs[j]) + be[j], 0.f);
    }
    s16x8 o;
    #pragma unroll
    for (int j = 0; j < 8; ++j) o[j] = (short)f2bu(acc[j]);
    *(s16x8*)(z + (size_t)f * H + c8) = o;
}

// Fused GINE MLP: h = (h + W2@relu(W1@z + b1) + b2) * valid, bf16 MFMA.
__global__ __launch_bounds__(256) void k_mlp_fused(
    const float* __restrict__ W1, const float* __restrict__ b1,
    const float* __restrict__ W2, const float* __restrict__ b2,
    const bf16* __restrict__ z, const int* __restrict__ node_ids,
    bf16* __restrict__ h) {
    __shared__ unsigned short zt[128][LDW];
    __shared__ unsigned short mt[128][LDW];
    __shared__ float validf[128];

    int tid = threadIdx.x;
    int w = tid >> 6;
    int l = tid & 63;
    int brow0 = blockIdx.x * 128;

    {
        int r = tid >> 1, c0 = (tid & 1) * 64;
        const s16x8* zr = (const s16x8*)(z + (size_t)(brow0 + r) * H + c0);
        #pragma unroll
        for (int i = 0; i < 8; ++i)
            *(s16x8*)&zt[r][c0 + i * 8] = zr[i];
        if (tid < 128) validf[tid] = (node_ids[brow0 + tid] >= 0) ? 1.f : 0.f;
    }

    s16x8 bw1[2][4], bw2[2][4];
    float b1c[2], b2c[2];
    #pragma unroll
    for (int nt = 0; nt < 2; ++nt) {
        int col = w * 32 + nt * 16 + (l & 15);
        b1c[nt] = b1[col];
        b2c[nt] = b2[col];
        #pragma unroll
        for (int kt = 0; kt < 4; ++kt) {
            int k0 = kt * 32 + (l >> 4) * 8;
            #pragma unroll
            for (int j = 0; j < 8; ++j) {
                bw1[nt][kt][j] = (short)f2bu(W1[(size_t)(k0 + j) * H + col]);
                bw2[nt][kt][j] = (short)f2bu(W2[(size_t)(k0 + j) * H + col]);
            }
        }
    }
    __syncthreads();

    f32x4 acc[8][2];
    #pragma unroll
    for (int mt_i = 0; mt_i < 8; ++mt_i)
        #pragma unroll
        for (int nt = 0; nt < 2; ++nt)
            acc[mt_i][nt] = f32x4{0.f, 0.f, 0.f, 0.f};
    #pragma unroll
    for (int kt = 0; kt < 4; ++kt) {
        #pragma unroll
        for (int mt_i = 0; mt_i < 8; ++mt_i) {
            s16x8 a = *(const s16x8*)&zt[mt_i * 16 + (l & 15)][kt * 32 + (l >> 4) * 8];
            acc[mt_i][0] = __builtin_amdgcn_mfma_f32_16x16x32_bf16(a, bw1[0][kt], acc[mt_i][0], 0, 0, 0);
            acc[mt_i][1] = __builtin_amdgcn_mfma_f32_16x16x32_bf16(a, bw1[1][kt], acc[mt_i][1], 0, 0, 0);
        }
    }
    #pragma unroll
    for (int mt_i = 0; mt_i < 8; ++mt_i) {
        #pragma unroll
        for (int nt = 0; nt < 2; ++nt) {
            int col = w * 32 + nt * 16 + (l & 15);
            #pragma unroll
            for (int r = 0; r < 4; ++r) {
                int row = mt_i * 16 + (l >> 4) * 4 + r;
                mt[row][col] = f2bu(fmaxf(acc[mt_i][nt][r] + b1c[nt], 0.f));
            }
        }
    }
    __syncthreads();

    #pragma unroll
    for (int mt_i = 0; mt_i < 8; ++mt_i)
        #pragma unroll
        for (int nt = 0; nt < 2; ++nt)
            acc[mt_i][nt] = f32x4{0.f, 0.f, 0.f, 0.f};
    #pragma unroll
    for (int kt = 0; kt < 4; ++kt) {
        #pragma unroll
        for (int mt_i = 0; mt_i < 8; ++mt_i) {
            s16x8 a = *(const s16x8*)&mt[mt_i * 16 + (l & 15)][kt * 32 + (l >> 4) * 8];
            acc[mt_i][0] = __builtin_amdgcn_mfma_f32_16x16x32_bf16(a, bw2[0][kt], acc[mt_i][0], 0, 0, 0);
            acc[mt_i][1] = __builtin_amdgcn_mfma_f32_16x16x32_bf16(a, bw2[1][kt], acc[mt_i][1], 0, 0, 0);
        }
    }
    #pragma unroll
    for (int mt_i = 0; mt_i < 8; ++mt_i) {
        #pragma unroll
        for (int nt = 0; nt < 2; ++nt) {
            int col = w * 32 + nt * 16 + (l & 15);
            #pragma unroll
            for (int r = 0; r < 4; ++r) {
                int row = mt_i * 16 + (l >> 4) * 4 + r;
                size_t g = (size_t)(brow0 + row) * H + col;
                float hv = b2f(h[g]);
                h[g] = f2b((hv + acc[mt_i][nt][r] + b2c[nt]) * validf[row]);
            }
        }
    }
}

// ------------------------------------------------------------- Readout ---

__global__ void k_tok(const bf16* __restrict__ h, float* __restrict__ htok) {
    int idx = blockIdx.x * 256 + threadIdx.x;
    int s = idx >> 7, c = idx & 127;
    htok[idx] = b2f(h[(size_t)s * K_SUB * H + c]);
}

// K1: LN1 + QKV(MFMA) + attention + Wo(MFMA) + residual.
#define ROQ_STR 408

__global__ __launch_bounds__(256) void k_ro_attn(
    float* __restrict__ htok,
    const float* __restrict__ g1, const float* __restrict__ b1,
    const float* __restrict__ Wqkv, const float* __restrict__ bqkv,
    const float* __restrict__ Wo, const float* __restrict__ bo,
    const float* __restrict__ log_probs, const float* __restrict__ alpha_p) {
    __shared__ unsigned short xn[64][LDW];
    __shared__ unsigned short qkv[64][ROQ_STR];
    __shared__ float lpv[64];
    int tid = threadIdx.x;
    int w = tid >> 6, l = tid & 63;
    int g0 = blockIdx.x * 64;
    float alpha = alpha_p[0];

    {
        int t = tid >> 2, q = tid & 3;
        const float4* xr = (const float4*)(htok + (size_t)(g0 + t) * H + q * 32);
        float x[32]; float s = 0.f, ss = 0.f;
        #pragma unroll
        for (int i = 0; i < 8; ++i) {
            float4 v = xr[i];
            x[i * 4 + 0] = v.x; x[i * 4 + 1] = v.y; x[i * 4 + 2] = v.z; x[i * 4 + 3] = v.w;
            s += v.x + v.y + v.z + v.w;
            ss += v.x * v.x + v.y * v.y + v.z * v.z + v.w * v.w;
        }
        s += __shfl_xor(s, 1); ss += __shfl_xor(ss, 1);
        s += __shfl_xor(s, 2); ss += __shfl_xor(ss, 2);
        float mu = s * (1.f / 128.f);
        float var = ss * (1.f / 128.f) - mu * mu;
        float inv = rsqrtf(var + 1e-5f);
        #pragma unroll
        for (int i = 0; i < 32; ++i) {
            int c = q * 32 + i;
            xn[t][c] = f2bu((x[i] - mu) * inv * g1[c] + b1[c]);
        }
        if (tid < 64) {
            float lp = log_probs[g0 + tid];
            lpv[tid] = isfinite(lp) ? lp : 0.f;
        }
    }
    __syncthreads();

    s16x8 a[4][4];
    #pragma unroll
    for (int mt_i = 0; mt_i < 4; ++mt_i)
        #pragma unroll
        for (int kt = 0; kt < 4; ++kt)
            a[mt_i][kt] = *(const s16x8*)&xn[mt_i * 16 + (l & 15)][kt * 32 + (l >> 4) * 8];

    #pragma unroll
    for (int nt = 0; nt < 6; ++nt) {
        int col = w * 96 + nt * 16 + (l & 15);
        s16x8 bw[4];
        #pragma unroll
        for (int kt = 0; kt < 4; ++kt) {
            int k0 = kt * 32 + (l >> 4) * 8;
            #pragma unroll
            for (int j = 0; j < 8; ++j)
                bw[kt][j] = (short)f2bu(Wqkv[(size_t)(k0 + j) * 384 + col]);
        }
        f32x4 acc[4];
        #pragma unroll
        for (int mt_i = 0; mt_i < 4; ++mt_i) acc[mt_i] = f32x4{0.f, 0.f, 0.f, 0.f};
        #pragma unroll
        for (int kt = 0; kt < 4; ++kt)
            #pragma unroll
            for (int mt_i = 0; mt_i < 4; ++mt_i)
                acc[mt_i] = __builtin_amdgcn_mfma_f32_16x16x32_bf16(a[mt_i][kt], bw[kt], acc[mt_i], 0, 0, 0);
        float bb = bqkv[col];
        #pragma unroll
        for (int mt_i = 0; mt_i < 4; ++mt_i)
            #pragma unroll
            for (int r = 0; r < 4; ++r)
                qkv[mt_i * 16 + (l >> 4) * 4 + r][col] = f2bu(acc[mt_i][r] + bb);
    }
    __syncthreads();

    {
        int node = tid >> 4, hh = (tid >> 2) & 3, ii = tid & 3;
        int t0 = node * 4;
        float qv[32];
        #pragma unroll
        for (int j4 = 0; j4 < 4; ++j4) {
            s16x8 v = *(const s16x8*)&qkv[t0 + ii][hh * 32 + j4 * 8];
            #pragma unroll
            for (int j = 0; j < 8; ++j) qv[j4 * 8 + j] = rb2f(v[j]);
        }
        float sc[4];
        #pragma unroll
        for (int jj = 0; jj < 4; ++jj) {
            float d = 0.f;
            #pragma unroll
            for (int j4 = 0; j4 < 4; ++j4) {
                s16x8 kv = *(const s16x8*)&qkv[t0 + jj][128 + hh * 32 + j4 * 8];
                #pragma unroll
                for (int j = 0; j < 8; ++j) d += qv[j4 * 8 + j] * rb2f(kv[j]);
            }
            sc[jj] = d * 0.17677669529663689f + alpha * lpv[t0 + jj];
        }
        float mx = fmaxf(fmaxf(sc[0], sc[1]), fmaxf(sc[2], sc[3]));
        float p[4]; float se = 0.f;
        #pragma unroll
        for (int jj = 0; jj < 4; ++jj) { p[jj] = expf(sc[jj] - mx); se += p[jj]; }
        float inv = 1.f / se;
        #pragma unroll
        for (int jj = 0; jj < 4; ++jj) p[jj] *= inv;
        float ov[32];
        #pragma unroll
        for (int i = 0; i < 32; ++i) ov[i] = 0.f;
        #pragma unroll
        for (int jj = 0; jj < 4; ++jj) {
            #pragma unroll
            for (int j4 = 0; j4 < 4; ++j4) {
                s16x8 vv = *(const s16x8*)&qkv[t0 + jj][256 + hh * 32 + j4 * 8];
                #pragma unroll
                for (int j = 0; j < 8; ++j) ov[j4 * 8 + j] += p[jj] * rb2f(vv[j]);
            }
        }
        __syncthreads();
        #pragma unroll
        for (int j4 = 0; j4 < 4; ++j4) {
            s16x8 o8;
            #pragma unroll
            for (int j = 0; j < 8; ++j) o8[j] = (short)f2bu(ov[j4 * 8 + j]);
            *(s16x8*)&xn[t0 + ii][hh * 32 + j4 * 8] = o8;
        }
    }
    __syncthreads();

    s16x8 ao[4][4];
    #pragma unroll
    for (int mt_i = 0; mt_i < 4; ++mt_i)
        #pragma unroll
        for (int kt = 0; kt < 4; ++kt)
            ao[mt_i][kt] = *(const s16x8*)&xn[mt_i * 16 + (l & 15)][kt * 32 + (l >> 4) * 8];
    #pragma unroll
    for (int nt = 0; nt < 2; ++nt) {
        int col = w * 32 + nt * 16 + (l & 15);
        s16x8 bw[4];
        #pragma unroll
        for (int kt = 0; kt < 4; ++kt) {
            int k0 = kt * 32 + (l >> 4) * 8;
            #pragma unroll
            for (int j = 0; j < 8; ++j)
                bw[kt][j] = (short)f2bu(Wo[(size_t)(k0 + j) * H + col]);
        }
        f32x4 acc[4];
        #pragma unroll
        for (int mt_i = 0; mt_i < 4; ++mt_i) acc[mt_i] = f32x4{0.f, 0.f, 0.f, 0.f};
        #pragma unroll
        for (int kt = 0; kt < 4; ++kt)
            #pragma unroll
            for (int mt_i = 0; mt_i < 4; ++mt_i)
                acc[mt_i] = __builtin_amdgcn_mfma_f32_16x16x32_bf16(ao[mt_i][kt], bw[kt], acc[mt_i], 0, 0, 0);
        float bb = bo[col];
        #pragma unroll
        for (int mt_i = 0; mt_i < 4; ++mt_i)
            #pragma unroll
            for (int r = 0; r < 4; ++r) {
                int row = mt_i * 16 + (l >> 4) * 4 + r;
                size_t gg = (size_t)(g0 + row) * H + col;
                htok[gg] += acc[mt_i][r] + bb;
            }
    }
}

// K2: LN2 + FFN1(gelu) + FFN2 (K-blocked) + residual.
__global__ __launch_bounds__(256) void k_ro_ffn(
    float* __restrict__ htok,
    const float* __restrict__ g2, const float* __restrict__ b2,
    const float* __restrict__ Wf1, const float* __restrict__ bf1,
    const float* __restrict__ Wf2, const float* __restrict__ bf2) {
    __shared__ unsigned short xb[64][LDW];
    int tid = threadIdx.x;
    int w = tid >> 6, l = tid & 63;
    int g0 = blockIdx.x * 64;

    {
        int t = tid >> 2, q = tid & 3;
        const float4* xr = (const float4*)(htok + (size_t)(g0 + t) * H + q * 32);
        float x[32]; float s = 0.f, ss = 0.f;
        #pragma unroll
        for (int i = 0; i < 8; ++i) {
            float4 v = xr[i];
            x[i * 4 + 0] = v.x; x[i * 4 + 1] = v.y; x[i * 4 + 2] = v.z; x[i * 4 + 3] = v.w;
            s += v.x + v.y + v.z + v.w;
            ss += v.x * v.x + v.y * v.y + v.z * v.z + v.w * v.w;
        }
        s += __shfl_xor(s, 1); ss += __shfl_xor(ss, 1);
        s += __shfl_xor(s, 2); ss += __shfl_xor(ss, 2);
        float mu = s * (1.f / 128.f);
        float var = ss * (1.f / 128.f) - mu * mu;
        float inv = rsqrtf(var + 1e-5f);
        #pragma unroll
        for (int i = 0; i < 32; ++i) {
            int c = q * 32 + i;
            xb[t][c] = f2bu((x[i] - mu) * inv * g2[c] + b2[c]);
        }
    }
    __syncthreads();

    s16x8 a2[4][4];
    #pragma unroll
    for (int mt_i = 0; mt_i < 4; ++mt_i)
        #pragma unroll
        for (int kt = 0; kt < 4; ++kt)
            a2[mt_i][kt] = *(const s16x8*)&xb[mt_i * 16 + (l & 15)][kt * 32 + (l >> 4) * 8];
    __syncthreads();

    f32x4 acc2[4][2];
    #pragma unroll
    for (int mt_i = 0; mt_i < 4; ++mt_i)
        #pragma unroll
        for (int nt = 0; nt < 2; ++nt)
            acc2[mt_i][nt] = f32x4{0.f, 0.f, 0.f, 0.f};

    #pragma unroll
    for (int cc = 0; cc < 4; ++cc) {
        #pragma unroll
        for (int nt = 0; nt < 2; ++nt) {
            int colf = cc * 128 + w * 32 + nt * 16 + (l & 15);
            s16x8 bw[4];
            #pragma unroll
            for (int kt = 0; kt < 4; ++kt) {
                int k0 = kt * 32 + (l >> 4) * 8;
                #pragma unroll
                for (int j = 0; j < 8; ++j)
                    bw[kt][j] = (short)f2bu(Wf1[(size_t)(k0 + j) * FFN + colf]);
            }
            f32x4 accm[4];
            #pragma unroll
            for (int mt_i = 0; mt_i < 4; ++mt_i) accm[mt_i] = f32x4{0.f, 0.f, 0.f, 0.f};
            #pragma unroll
            for (int kt = 0; kt < 4; ++kt)
                #pragma unroll
                for (int mt_i = 0; mt_i < 4; ++mt_i)
                    accm[mt_i] = __builtin_amdgcn_mfma_f32_16x16x32_bf16(a2[mt_i][kt], bw[kt], accm[mt_i], 0, 0, 0);
            float bb = bf1[colf];
            int colw = w * 32 + nt * 16 + (l & 15);
            #pragma unroll
            for (int mt_i = 0; mt_i < 4; ++mt_i)
                #pragma unroll
                for (int r = 0; r < 4; ++r) {
                    float v = accm[mt_i][r] + bb;
                    v = v * 0.5f * (1.f + erff(v * 0.70710678118654752f));
                    xb[mt_i * 16 + (l >> 4) * 4 + r][colw] = f2bu(v);
                }
        }
        __syncthreads();
        s16x8 am[4][4];
        #pragma unroll
        for (int mt_i = 0; mt_i < 4; ++mt_i)
            #pragma unroll
            for (int kt = 0; kt < 4; ++kt)
                am[mt_i][kt] = *(const s16x8*)&xb[mt_i * 16 + (l & 15)][kt * 32 + (l >> 4) * 8];
        #pragma unroll
        for (int nt = 0; nt < 2; ++nt) {
            int colo = w * 32 + nt * 16 + (l & 15);
            s16x8 bw[4];
            #pragma unroll
            for (int kt = 0; kt < 4; ++kt) {
                int k0 = cc * 128 + kt * 32 + (l >> 4) * 8;
                #pragma unroll
                for (int j = 0; j < 8; ++j)
                    bw[kt][j] = (short)f2bu(Wf2[(size_t)(k0 + j) * H + colo]);
            }
            #pragma unroll
            for (int kt = 0; kt < 4; ++kt)
                #pragma unroll
                for (int mt_i = 0; mt_i < 4; ++mt_i)
                    acc2[mt_i][nt] = __builtin_amdgcn_mfma_f32_16x16x32_bf16(am[mt_i][kt], bw[kt], acc2[mt_i][nt], 0, 0, 0);
        }
        __syncthreads();
    }

    #pragma unroll
    for (int nt = 0; nt < 2; ++nt) {
        int col = w * 32 + nt * 16 + (l & 15);
        float bb = bf2[col];
        #pragma unroll
        for (int mt_i = 0; mt_i < 4; ++mt_i)
            #pragma unroll
            for (int r = 0; r < 4; ++r) {
                int row = mt_i * 16 + (l >> 4) * 4 + r;
                size_t gg = (size_t)(g0 + row) * H + col;
                htok[gg] += acc2[mt_i][nt][r] + bb;
            }
    }
}

__global__ __launch_bounds__(128) void k_nodeemb(const float* __restrict__ htok,
                                                 const float* __restrict__ og,
                                                 const float* __restrict__ ob,
                                                 float* __restrict__ nemb) {
    int n = blockIdx.x, c = threadIdx.x;
    const float* hr = htok + (size_t)n * 4 * H;
    float v = 0.25f * (hr[c] + hr[H + c] + hr[2 * H + c] + hr[3 * H + c]);
    float s = v, ss = v * v;
    #pragma unroll
    for (int m = 1; m < 64; m <<= 1) { s += __shfl_xor(s, m); ss += __shfl_xor(ss, m); }
    __shared__ float red[4];
    if ((threadIdx.x & 63) == 0) {
        red[(threadIdx.x >> 6) * 2] = s;
        red[(threadIdx.x >> 6) * 2 + 1] = ss;
    }
    __syncthreads();
    s = red[0] + red[2];
    ss = red[1] + red[3];
    float mu = s * (1.f / 128.f);
    float var = ss * (1.f / 128.f) - mu * mu;
    float inv = rsqrtf(var + 1e-5f);
    nemb[(size_t)n * H + c] = (v - mu) * inv * og[c] + ob[c];
}

__global__ __launch_bounds__(128) void k_out(const float* __restrict__ nemb,
                                             float* __restrict__ out) {
    int g = blockIdx.x, c = threadIdx.x;
    float acc = 0.f;
    for (int i = 0; i < 128; ++i) acc += nemb[(size_t)(g * 128 + i) * H + c];
    out[g * H + c] = acc;
}

// ------------------------------------------------------------- launch ----

extern "C" void kernel_launch(void* const* d_in, const int* in_sizes, int n_in,
                              void* d_out, int out_size, void* d_ws, size_t ws_size,
                              hipStream_t stream) {
    (void)in_sizes; (void)n_in; (void)out_size;
    const int* edge_index    = (const int*)d_in[0];
    const int* intra_ei      = (const int*)d_in[1];
    const int* edge_attr_ids = (const int*)d_in[2];
    const int* intra_ea_ids  = (const int*)d_in[3];
    const int* node_ids      = (const int*)d_in[4];
    const int* x_ids         = (const int*)d_in[5];
    const float* log_probs   = (const float*)d_in[7];
    const float* atom_emb    = (const float*)d_in[8];
    const float* bond_emb    = (const float*)d_in[9];
    const float* rwse_W      = (const float*)d_in[10];
    const float* rwse_b      = (const float*)d_in[11];
    const float* gnn_W1      = (const float*)d_in[12];
    const float* gnn_b1      = (const float*)d_in[13];
    const float* gnn_W2      = (const float*)d_in[14];
    const float* gnn_b2      = (const float*)d_in[15];
    const float* ro_ln1_g    = (const float*)d_in[16];
    const float* ro_ln1_b    = (const float*)d_in[17];
    const float* ro_Wqkv     = (const float*)d_in[18];
    const float* ro_bqkv     = (const float*)d_in[19];
    const float* ro_Wo       = (const float*)d_in[20];
    const float* ro_bo       = (const float*)d_in[21];
    const float* ro_ln2_g    = (const float*)d_in[22];
    const float* ro_ln2_b    = (const float*)d_in[23];
    const float* ro_Wf1      = (const float*)d_in[24];
    const float* ro_bf1      = (const float*)d_in[25];
    const float* ro_Wf2      = (const float*)d_in[26];
    const float* ro_bf2      = (const float*)d_in[27];
    const float* out_ln_g    = (const float*)d_in[28];
    const float* out_ln_b    = (const float*)d_in[29];
    const float* ht_alpha    = (const float*)d_in[30];

    char* ws = (char*)d_ws;
    size_t off = 0;
    auto alloc = [&](size_t nbytes) {
        char* p = ws + off;
        off += (nbytes + 255) & ~(size_t)255;
        return p;
    };
    float* T       = (float*)alloc((size_t)B_GRAPHS * 128 * 128 * 4);
    float* rwse    = (float*)alloc((size_t)N_TOTAL * STEPS * 4);
    float* base    = (float*)alloc((size_t)N_TOTAL * H * 4);
    float* gbuf    = (float*)alloc((size_t)2 * N_TOTAL * H * 4);
    float* htok    = (float*)alloc((size_t)S_SUB * H * 4);
    float* nemb    = (float*)alloc((size_t)N_TOTAL * H * 4);
    bf16*  z       = (bf16*)alloc((size_t)FLATN * H * 2);
    bf16*  h       = (bf16*)alloc((size_t)FLATN * H * 2);
    int*   deg     = (int*)alloc((size_t)FLATN * 4);
    int*   rp      = (int*)alloc((size_t)FLATN * 4);
    int*   cursor  = (int*)alloc((size_t)FLATN * 4);
    int*   payload = (int*)alloc((size_t)E_INTRA * 4);
    int*   degN    = (int*)alloc((size_t)N_TOTAL * 4);
    int*   rpN     = (int*)alloc((size_t)N_TOTAL * 4);
    int*   cursorN = (int*)alloc((size_t)N_TOTAL * 4);
    int*   poolidx = (int*)alloc((size_t)FLATN * 4);
    int*   bsum    = (int*)alloc(1024 * 4);
    int*   bsumN   = (int*)alloc(16 * 4);
    float* gpool   = gbuf;
    float* gagg    = gbuf + (size_t)N_TOTAL * H;

    if (off > ws_size) return;

    // ---- CSR build ----
    k_zeroi<<<FLATN / 256, 256, 0, stream>>>(deg, FLATN);
    k_zeroi<<<N_TOTAL / 256, 256, 0, stream>>>(degN, N_TOTAL);
    k_hist_edge<<<E_INTRA / 256, 256, 0, stream>>>(intra_ei, deg);
    k_hist_pool<<<FLATN / 256, 256, 0, stream>>>(node_ids, degN);
    k_scan_blk<<<FLATN / 256, 256, 0, stream>>>(deg, rp, bsum, FLATN);
    k_scan_top<<<1, 256, 0, stream>>>(bsum, FLATN / 256);
    k_scan_add<<<FLATN / 256, 256, 0, stream>>>(rp, bsum, cursor, FLATN);
    k_scan_blk<<<N_TOTAL / 256, 256, 0, stream>>>(degN, rpN, bsumN, N_TOTAL);
    k_scan_top<<<1, 256, 0, stream>>>(bsumN, N_TOTAL / 256);
    k_scan_add<<<N_TOTAL / 256, 256, 0, stream>>>(rpN, bsumN, cursorN, N_TOTAL);
    k_scatter_edge<<<E_INTRA / 256, 256, 0, stream>>>(intra_ei, intra_ea_ids, cursor, payload);
    k_scatter_pool<<<FLATN / 256, 256, 0, stream>>>(node_ids, cursorN, poolidx);

    // ---- RWSE ----
    k_zero4<<<(B_GRAPHS * 128 * 128 / 4 + 255) / 256, 256, 0, stream>>>((float4*)T, B_GRAPHS * 128 * 128 / 4);
    k_adj<<<E_GLOB / 256, 256, 0, stream>>>(edge_index, T);
    k_rownorm<<<(B_GRAPHS * 128) / 4, 256, 0, stream>>>(T);
    k_rwse_mfma<<<B_GRAPHS * RWG, 256, 0, stream>>>(T, rwse);
    k_rwse_head<<<(N_TOTAL * H) / 256, 256, 0, stream>>>(rwse, rwse_W, rwse_b, atom_emb, x_ids, base);
    k_hinit<<<(FLATN * H) / 256, 256, 0, stream>>>(base, node_ids, h);

    // ---- GNN layers ----
    for (int l = 0; l < L_GNN; ++l) {
        k_zero4<<<(N_TOTAL * H / 4 + 255) / 256, 256, 0, stream>>>((float4*)gagg, N_TOTAL * H / 4);
        k_pool_csr<<<(N_TOTAL * H) / 256, 256, 0, stream>>>(h, rpN, degN, poolidx, gpool);
        k_gagg<<<(E_GLOB * H) / 256, 256, 0, stream>>>(gpool, bond_emb, edge_index, edge_attr_ids, gagg);
        k_aggz<<<(FLATN * 16) / 256, 256, 0, stream>>>(h, gagg, bond_emb, node_ids, rp, deg, payload, z);
        k_mlp_fused<<<FLATN / 128, 256, 0, stream>>>(
            gnn_W1 + (size_t)l * H * H, gnn_b1 + l * H,
            gnn_W2 + (size_t)l * H * H, gnn_b2 + l * H,
            z, node_ids, h);
    }

    // ---- Readout ----
    k_tok<<<(S_SUB * H) / 256, 256, 0, stream>>>(h, htok);
    for (int l = 0; l < L_RO; ++l) {
        k_ro_attn<<<S_SUB * M_TOK / 64 / 4, 256, 0, stream>>>(htok,
            ro_ln1_g + l * H, ro_ln1_b + l * H,
            ro_Wqkv + (size_t)l * H * 3 * H, ro_bqkv + l * 3 * H,
            ro_Wo + (size_t)l * H * H, ro_bo + l * H,
            log_probs, ht_alpha);
        k_ro_ffn<<<S_SUB * M_TOK / 64 / 4, 256, 0, stream>>>(htok,
            ro_ln2_g + l * H, ro_ln2_b + l * H,
            ro_Wf1 + (size_t)l * H * FFN, ro_bf1 + l * FFN,
            ro_Wf2 + (size_t)l * FFN * H, ro_bf2 + l * H);
    }
    k_nodeemb<<<N_TOTAL, 128, 0, stream>>>(htok, out_ln_g, out_ln_b, nemb);
    k_out<<<B_GRAPHS, 128, 0, stream>>>(nemb, (float*)d_out);
}